// Round 1
// baseline (371.953 us; speedup 1.0000x reference)
//
#include <hip/hip_runtime.h>
#include <stdint.h>

#define HEADS 16
#define HD 128
#define S_TXT 256
#define S_IMG 2048
#define S_ALL 2304
#define DMODEL 2048
#define N_QKV 6144
#define INNER 2048
#define ATT_EPS 1e-5f
#define ATT_SCALE 0.08838834764831845f

typedef __attribute__((ext_vector_type(8))) __bf16 bf16x8;
typedef __attribute__((ext_vector_type(4))) float f32x4;
typedef __attribute__((ext_vector_type(4))) uint32_t u32x4;

__device__ __forceinline__ uint16_t f2bf(float f) {
  union { float f; uint32_t u; } v; v.f = f;
  uint32_t r = (v.u + 0x7FFF + ((v.u >> 16) & 1)) >> 16;
  return (uint16_t)r;
}
__device__ __forceinline__ float bf2f(uint16_t h) {
  union { float f; uint32_t u; } v; v.u = ((uint32_t)h) << 16;
  return v.f;
}

// async global->LDS, 16B per lane; lptr is wave-uniform base (HW adds lane*16)
__device__ __forceinline__ void async_cp16(const void* g, void* l) {
  __builtin_amdgcn_global_load_lds(
      (const __attribute__((address_space(1))) void*)g,
      (__attribute__((address_space(3))) void*)l, 16, 0, 0);
}

// ---------------- converts ----------------
__global__ __launch_bounds__(256) void k_cvt(const float* __restrict__ src,
                                             uint16_t* __restrict__ dst, int n4) {
  int i = blockIdx.x * 256 + threadIdx.x;
  int stride = gridDim.x * 256;
  for (; i < n4; i += stride) {
    float4 v = ((const float4*)src)[i];
    uint16_t o[4];
    o[0] = f2bf(v.x); o[1] = f2bf(v.y); o[2] = f2bf(v.z); o[3] = f2bf(v.w);
    ((uint2*)dst)[i] = *(const uint2*)o;
  }
}

// dst[C][R] = bf16(src[R][C]); 64x64 tiles
__global__ __launch_bounds__(256) void k_cvt_t(const float* __restrict__ src,
                                               uint16_t* __restrict__ dst, int R, int C) {
  __shared__ float t[64][65];
  int ntr = R >> 6;
  int tr = blockIdx.x % ntr, tc = blockIdx.x / ntr;
  int tid = threadIdx.x;
#pragma unroll
  for (int j = 0; j < 16; ++j) {
    int idx = tid + j * 256; int r = idx >> 6, c = idx & 63;
    t[r][c] = src[(size_t)(tr * 64 + r) * C + tc * 64 + c];
  }
  __syncthreads();
#pragma unroll
  for (int j = 0; j < 16; ++j) {
    int idx = tid + j * 256; int r2 = idx >> 6, c2 = idx & 63;
    dst[(size_t)(tc * 64 + r2) * R + tr * 64 + c2] = f2bf(t[c2][r2]);
  }
}

// ---------------- GEMM: C[M][N] = A[M][K](bf16) * BT[N][K](bf16) + bias ----------------
// two row-segments routed by blockIdx.y; 128x128 tile, BK=32, 4 waves (2x2 of 64x64)
template <bool OUT_BF16>
__global__ __launch_bounds__(256) void k_gemm(
    const uint16_t* __restrict__ A0, const uint16_t* __restrict__ B0,
    const float* __restrict__ bias0, void* __restrict__ C0,
    const uint16_t* __restrict__ A1, const uint16_t* __restrict__ B1,
    const float* __restrict__ bias1, void* __restrict__ C1,
    int seg0_tiles, int N, int K) {
  __shared__ __align__(16) uint16_t At[128 * 32];
  __shared__ __align__(16) uint16_t Bt[128 * 32];
  int bn = blockIdx.x, bm = blockIdx.y;
  const uint16_t* A; const uint16_t* B; const float* bias; void* C; int mrow;
  if (bm < seg0_tiles) { A = A0; B = B0; bias = bias0; C = C0; mrow = bm * 128; }
  else { A = A1; B = B1; bias = bias1; C = C1; mrow = (bm - seg0_tiles) * 128; }
  int tid = threadIdx.x, lane = tid & 63, w = tid >> 6;
  int g = lane >> 4, li = lane & 15;
  int wm = w >> 1, wn = w & 1;
  f32x4 acc[4][4] = {};
  for (int kt = 0; kt < K; kt += 32) {
#pragma unroll
    for (int j = 0; j < 2; ++j) {
      int ci = (w * 2 + j) * 64 + lane;
      int row = ci >> 2, c = ci & 3;
      async_cp16(A + (size_t)(mrow + row) * K + kt + 8 * c, (char*)At + (w * 2 + j) * 1024);
    }
#pragma unroll
    for (int j = 0; j < 2; ++j) {
      int ci = (w * 2 + j) * 64 + lane;
      int row = ci >> 2, c = ci & 3;
      async_cp16(B + (size_t)(bn * 128 + row) * K + kt + 8 * c, (char*)Bt + (w * 2 + j) * 1024);
    }
    __syncthreads();
    bf16x8 af[4], bfv[4];
#pragma unroll
    for (int mi = 0; mi < 4; ++mi) {
      int row = wm * 64 + mi * 16 + li;
      af[mi] = __builtin_bit_cast(bf16x8, *(const u32x4*)((const char*)At + row * 64 + g * 16));
    }
#pragma unroll
    for (int ni = 0; ni < 4; ++ni) {
      int row = wn * 64 + ni * 16 + li;
      bfv[ni] = __builtin_bit_cast(bf16x8, *(const u32x4*)((const char*)Bt + row * 64 + g * 16));
    }
#pragma unroll
    for (int mi = 0; mi < 4; ++mi)
#pragma unroll
      for (int ni = 0; ni < 4; ++ni)
        acc[mi][ni] = __builtin_amdgcn_mfma_f32_16x16x32_bf16(af[mi], bfv[ni], acc[mi][ni], 0, 0, 0);
    __syncthreads();
  }
#pragma unroll
  for (int mi = 0; mi < 4; ++mi) {
#pragma unroll
    for (int ni = 0; ni < 4; ++ni) {
      int col = bn * 128 + wn * 64 + ni * 16 + li;
      float bv = bias ? bias[col] : 0.0f;
#pragma unroll
      for (int i = 0; i < 4; ++i) {
        int r = mrow + wm * 64 + mi * 16 + 4 * g + i;
        float v = acc[mi][ni][i] + bv;
        if (OUT_BF16) ((uint16_t*)C)[(size_t)r * N + col] = f2bf(v);
        else          ((float*)C)[(size_t)r * N + col] = v;
      }
    }
  }
}

// ---------------- postprocess: rmsnorm + rope + scale; emit Q,K [H][S][D], V^T [H][D][S] ----------------
__global__ __launch_bounds__(256) void k_post(
    const uint16_t* __restrict__ qkv_img, const uint16_t* __restrict__ qkv_txt,
    const float* __restrict__ fcos, const float* __restrict__ fsin,
    const float* __restrict__ wq, const float* __restrict__ wk,
    const float* __restrict__ waq, const float* __restrict__ wak,
    uint16_t* __restrict__ Qo, uint16_t* __restrict__ Ko, uint16_t* __restrict__ VTo) {
  int s = blockIdx.x;
  const uint16_t* row = (s < S_TXT) ? qkv_txt + (size_t)s * N_QKV
                                    : qkv_img + (size_t)(s - S_TXT) * N_QKV;
  const float* wqp = (s < S_TXT) ? waq : wq;
  const float* wkp = (s < S_TXT) ? wak : wk;
  int tid = threadIdx.x, lane = tid & 63, w = tid >> 6;
  int h = w * 4 + (lane >> 4);
  int d0 = (lane & 15) * 8;
  float cs[8], sn[8];
#pragma unroll
  for (int j = 0; j < 8; ++j) {
    cs[j] = fcos[s * HD + d0 + j];
    sn[j] = fsin[s * HD + d0 + j];
  }
#pragma unroll
  for (int part = 0; part < 2; ++part) {  // 0 = Q, 1 = K
    const uint16_t* src = row + part * INNER + h * HD + d0;
    u32x4 raw = *(const u32x4*)src;
    const uint16_t* rp = (const uint16_t*)&raw;
    float x[8], ss = 0.f;
#pragma unroll
    for (int j = 0; j < 8; ++j) { x[j] = bf2f(rp[j]); ss += x[j] * x[j]; }
    ss += __shfl_xor(ss, 1); ss += __shfl_xor(ss, 2);
    ss += __shfl_xor(ss, 4); ss += __shfl_xor(ss, 8);
    float rn = rsqrtf(ss * (1.0f / HD) + ATT_EPS);
    const float* wp = part ? wkp : wqp;
#pragma unroll
    for (int j = 0; j < 8; ++j) x[j] = x[j] * rn * wp[d0 + j];
    float y[8];
#pragma unroll
    for (int j = 0; j < 8; j += 2) {
      y[j]     = x[j] * cs[j] - x[j + 1] * sn[j];
      y[j + 1] = x[j + 1] * cs[j + 1] + x[j] * sn[j + 1];
    }
    float sc = part ? 1.0f : ATT_SCALE;
    uint16_t ov[8];
#pragma unroll
    for (int j = 0; j < 8; ++j) ov[j] = f2bf(y[j] * sc);
    uint16_t* dst = (part ? Ko : Qo) + ((size_t)h * S_ALL + s) * HD + d0;
    *(u32x4*)dst = *(const u32x4*)ov;
  }
  {  // V -> V^T scatter
    u32x4 raw = *(const u32x4*)(row + 2 * INNER + h * HD + d0);
    const uint16_t* rp = (const uint16_t*)&raw;
#pragma unroll
    for (int j = 0; j < 8; ++j)
      VTo[((size_t)h * HD + d0 + j) * S_ALL + s] = rp[j];
  }
}

// ---------------- attention ----------------
// block: 4 waves, 64 q rows (16/wave); loop KV tiles of 64; K [64][128] & V^T [128][64] in LDS (XOR-swizzled)
__global__ __launch_bounds__(256) void k_attn(
    const uint16_t* __restrict__ Qg, const uint16_t* __restrict__ Kg,
    const uint16_t* __restrict__ VTg, uint16_t* __restrict__ Og) {
  __shared__ __align__(16) uint16_t Kt[64 * 128];
  __shared__ __align__(16) uint16_t Vt[128 * 64];
  __shared__ __align__(16) uint16_t Pl[4][16 * 72];
  int bid = blockIdx.x;
  int h = bid / (S_ALL / 64), qt = bid % (S_ALL / 64);
  int tid = threadIdx.x, lane = tid & 63, w = tid >> 6;
  int g = lane >> 4, li = lane & 15;

  bf16x8 qf[4];
  {
    int qrow = qt * 64 + w * 16 + li;
    const uint16_t* qp = Qg + ((size_t)h * S_ALL + qrow) * HD;
#pragma unroll
    for (int kc = 0; kc < 4; ++kc)
      qf[kc] = __builtin_bit_cast(bf16x8, *(const u32x4*)(qp + kc * 32 + g * 8));
  }
  f32x4 o[8] = {};
  float m0[4], lsum[4];
#pragma unroll
  for (int i = 0; i < 4; ++i) { m0[i] = -1e30f; lsum[i] = 0.f; }

  for (int t = 0; t < S_ALL / 64; ++t) {
    // stage K tile (rows=key, 16 chunks/row, chunk' = chunk ^ (key&15))
#pragma unroll
    for (int j = 0; j < 4; ++j) {
      int ci = (w * 4 + j) * 64 + lane;
      int row = ci >> 4, cc = (ci & 15) ^ (row & 15);
      async_cp16(Kg + ((size_t)h * S_ALL + t * 64 + row) * HD + 8 * cc,
                 (char*)Kt + (w * 4 + j) * 1024);
    }
    // stage V^T tile (rows=d, 8 chunks/row, chunk' = chunk ^ (d&7))
#pragma unroll
    for (int j = 0; j < 4; ++j) {
      int ci = (w * 4 + j) * 64 + lane;
      int row = ci >> 3, cc = (ci & 7) ^ (row & 7);
      async_cp16(VTg + ((size_t)h * HD + row) * S_ALL + t * 64 + 8 * cc,
                 (char*)Vt + (w * 4 + j) * 1024);
    }
    __syncthreads();

    // QK^T: scores 16q x 64k
    f32x4 sc[4];
#pragma unroll
    for (int kb = 0; kb < 4; ++kb) {
      sc[kb] = (f32x4){0.f, 0.f, 0.f, 0.f};
#pragma unroll
      for (int kc = 0; kc < 4; ++kc) {
        int key = kb * 16 + li;
        int chunk = (4 * kc + g) ^ li;
        bf16x8 kf = __builtin_bit_cast(bf16x8, *(const u32x4*)((const char*)Kt + key * 256 + chunk * 16));
        sc[kb] = __builtin_amdgcn_mfma_f32_16x16x32_bf16(qf[kc], kf, sc[kb], 0, 0, 0);
      }
    }
    // online softmax
    float p[4][4], sf[4];
#pragma unroll
    for (int i = 0; i < 4; ++i) {
      float tm = fmaxf(fmaxf(sc[0][i], sc[1][i]), fmaxf(sc[2][i], sc[3][i]));
      tm = fmaxf(tm, __shfl_xor(tm, 1));
      tm = fmaxf(tm, __shfl_xor(tm, 2));
      tm = fmaxf(tm, __shfl_xor(tm, 4));
      tm = fmaxf(tm, __shfl_xor(tm, 8));
      float mn = fmaxf(m0[i], tm);
      sf[i] = __expf(m0[i] - mn);
      m0[i] = mn;
      float rs = 0.f;
#pragma unroll
      for (int kb = 0; kb < 4; ++kb) { p[kb][i] = __expf(sc[kb][i] - mn); rs += p[kb][i]; }
      rs += __shfl_xor(rs, 1); rs += __shfl_xor(rs, 2);
      rs += __shfl_xor(rs, 4); rs += __shfl_xor(rs, 8);
      lsum[i] = lsum[i] * sf[i] + rs;
    }
#pragma unroll
    for (int db = 0; db < 8; ++db)
#pragma unroll
      for (int i = 0; i < 4; ++i) o[db][i] *= sf[i];
    // write P (per-wave region, row stride 72 elems = 144B)
    uint16_t* pw = &Pl[w][0];
#pragma unroll
    for (int kb = 0; kb < 4; ++kb)
#pragma unroll
      for (int i = 0; i < 4; ++i)
        pw[(4 * g + i) * 72 + kb * 16 + li] = f2bf(p[kb][i]);
    // PV
#pragma unroll
    for (int kc2 = 0; kc2 < 2; ++kc2) {
      bf16x8 pf = __builtin_bit_cast(bf16x8,
          *(const u32x4*)((const char*)&Pl[w][0] + li * 144 + kc2 * 64 + g * 16));
#pragma unroll
      for (int db = 0; db < 8; ++db) {
        int vrow = db * 16 + li;
        int chunk = (4 * kc2 + g) ^ (li & 7);
        bf16x8 vf = __builtin_bit_cast(bf16x8, *(const u32x4*)((const char*)Vt + vrow * 128 + chunk * 16));
        o[db] = __builtin_amdgcn_mfma_f32_16x16x32_bf16(pf, vf, o[db], 0, 0, 0);
      }
    }
    __syncthreads();
  }
  float inv[4];
#pragma unroll
  for (int i = 0; i < 4; ++i) inv[i] = 1.0f / lsum[i];
  int qrow = qt * 64 + w * 16;
#pragma unroll
  for (int db = 0; db < 8; ++db)
#pragma unroll
    for (int i = 0; i < 4; ++i)
      Og[(size_t)(qrow + 4 * g + i) * INNER + h * HD + db * 16 + li] = f2bf(o[db][i] * inv[i]);
}

// ---------------- launch ----------------
extern "C" void kernel_launch(void* const* d_in, const int* in_sizes, int n_in,
                              void* d_out, int out_size, void* d_ws, size_t ws_size,
                              hipStream_t stream) {
  const float* hidden = (const float*)d_in[0];
  const float* enc    = (const float*)d_in[1];
  const float* fcos   = (const float*)d_in[2];
  const float* fsin   = (const float*)d_in[3];
  const float* Wqkv   = (const float*)d_in[4];
  const float* Wqkva  = (const float*)d_in[5];
  const float* bqkva  = (const float*)d_in[6];
  const float* nqw    = (const float*)d_in[7];
  const float* nkw    = (const float*)d_in[8];
  const float* naqw   = (const float*)d_in[9];
  const float* nakw   = (const float*)d_in[10];
  const float* Wout   = (const float*)d_in[11];
  const float* bout   = (const float*)d_in[12];
  const float* Wadd   = (const float*)d_in[13];
  const float* badd   = (const float*)d_in[14];
  float* out_img = (float*)d_out;
  float* out_enc = (float*)d_out + (size_t)S_IMG * DMODEL;

  char* ws = (char*)d_ws;
  size_t off = 0;
  auto alloc = [&](size_t bytes) {
    char* p = ws + off;
    off += (bytes + 255) & ~(size_t)255;
    return p;
  };
  uint16_t* hs_bf   = (uint16_t*)alloc((size_t)S_IMG * DMODEL * 2);
  uint16_t* enc_bf  = (uint16_t*)alloc((size_t)S_TXT * DMODEL * 2);
  char*     wqkv_base = alloc((size_t)N_QKV * DMODEL * 2 * 2);  // WqkvT + WqkvaT (reused later)
  uint16_t* WqkvT   = (uint16_t*)wqkv_base;
  uint16_t* WqkvaT  = (uint16_t*)(wqkv_base + (size_t)N_QKV * DMODEL * 2);
  uint16_t* WoutT   = (uint16_t*)alloc((size_t)DMODEL * INNER * 2);
  uint16_t* WaddT   = (uint16_t*)alloc((size_t)DMODEL * INNER * 2);
  uint16_t* qkv_img = (uint16_t*)alloc((size_t)S_IMG * N_QKV * 2);
  uint16_t* qkv_txt = (uint16_t*)alloc((size_t)S_TXT * N_QKV * 2);
  // overlay Q/K/VT/attn on the Wqkv(T) region (dead after qkv GEMM): 37.8MB < 50.3MB
  uint16_t* Qb   = (uint16_t*)wqkv_base;
  uint16_t* Kb   = Qb + (size_t)HEADS * S_ALL * HD;
  uint16_t* VTb  = Kb + (size_t)HEADS * S_ALL * HD;
  uint16_t* attn = VTb + (size_t)HEADS * S_ALL * HD;

  k_cvt<<<1024, 256, 0, stream>>>(hidden, hs_bf, S_IMG * DMODEL / 4);
  k_cvt<<<256, 256, 0, stream>>>(enc, enc_bf, S_TXT * DMODEL / 4);
  k_cvt_t<<<(DMODEL / 64) * (N_QKV / 64), 256, 0, stream>>>(Wqkv, WqkvT, DMODEL, N_QKV);
  k_cvt_t<<<(DMODEL / 64) * (N_QKV / 64), 256, 0, stream>>>(Wqkva, WqkvaT, DMODEL, N_QKV);
  k_cvt_t<<<(INNER / 64) * (DMODEL / 64), 256, 0, stream>>>(Wout, WoutT, INNER, DMODEL);
  k_cvt_t<<<(INNER / 64) * (DMODEL / 64), 256, 0, stream>>>(Wadd, WaddT, INNER, DMODEL);

  dim3 gq(N_QKV / 128, (S_TXT + S_IMG) / 128);
  k_gemm<true><<<gq, 256, 0, stream>>>(enc_bf, WqkvaT, bqkva, qkv_txt,
                                       hs_bf, WqkvT, nullptr, qkv_img,
                                       S_TXT / 128, N_QKV, DMODEL);

  k_post<<<S_ALL, 256, 0, stream>>>(qkv_img, qkv_txt, fcos, fsin,
                                    nqw, nkw, naqw, nakw, Qb, Kb, VTb);

  k_attn<<<HEADS * (S_ALL / 64), 256, 0, stream>>>(Qb, Kb, VTb, attn);

  dim3 go(DMODEL / 128, S_ALL / 128);
  k_gemm<false><<<go, 256, 0, stream>>>(attn, WaddT, badd, out_enc,
                                        attn + (size_t)S_TXT * INNER, WoutT, bout, out_img,
                                        S_TXT / 128, DMODEL, DMODEL);
}

// Round 2
// 341.952 us; speedup vs baseline: 1.0877x; 1.0877x over previous
//
#include <hip/hip_runtime.h>
#include <stdint.h>

#define HEADS 16
#define HD 128
#define S_TXT 256
#define S_IMG 2048
#define S_ALL 2304
#define DMODEL 2048
#define N_QKV 6144
#define INNER 2048
#define ATT_EPS 1e-5f
#define ATT_SCALE 0.08838834764831845f
#define LOG2E 1.4426950408889634f
#define MBOUND 16.5f
#define NT (S_ALL / 64)

typedef __attribute__((ext_vector_type(8))) __bf16 bf16x8;
typedef __attribute__((ext_vector_type(4))) float f32x4;
typedef __attribute__((ext_vector_type(4))) uint32_t u32x4;

__device__ __forceinline__ uint16_t f2bf(float f) {
  union { float f; uint32_t u; } v; v.f = f;
  uint32_t r = (v.u + 0x7FFF + ((v.u >> 16) & 1)) >> 16;
  return (uint16_t)r;
}
__device__ __forceinline__ float bf2f(uint16_t h) {
  union { float f; uint32_t u; } v; v.u = ((uint32_t)h) << 16;
  return v.f;
}
__device__ __forceinline__ float fexp2(float x) {
#if __has_builtin(__builtin_amdgcn_exp2f)
  return __builtin_amdgcn_exp2f(x);
#else
  return __expf(x * 0.69314718055994531f);
#endif
}

// async global->LDS, 16B per lane; lds ptr is wave-uniform base (HW adds lane*16)
__device__ __forceinline__ void async_cp16(const void* g, void* l) {
  __builtin_amdgcn_global_load_lds(
      (const __attribute__((address_space(1))) void*)g,
      (__attribute__((address_space(3))) void*)l, 16, 0, 0);
}

// ---------------- converts ----------------
__global__ __launch_bounds__(256) void k_cvt(const float* __restrict__ src,
                                             uint16_t* __restrict__ dst, int n4) {
  int i = blockIdx.x * 256 + threadIdx.x;
  int stride = gridDim.x * 256;
  for (; i < n4; i += stride) {
    float4 v = ((const float4*)src)[i];
    uint16_t o[4];
    o[0] = f2bf(v.x); o[1] = f2bf(v.y); o[2] = f2bf(v.z); o[3] = f2bf(v.w);
    ((uint2*)dst)[i] = *(const uint2*)o;
  }
}

// dst[C][R] = bf16(src[R][C]); 64x64 tiles, vectorized (float4 in, uint2 out)
__global__ __launch_bounds__(256) void k_cvt_t(const float* __restrict__ src,
                                               uint16_t* __restrict__ dst, int R, int C) {
  __shared__ float t[64][68];
  int ntr = R >> 6;
  int tr = blockIdx.x % ntr, tc = blockIdx.x / ntr;
  int tid = threadIdx.x;
  int rr = tid >> 4, c4 = (tid & 15) * 4;
#pragma unroll
  for (int j = 0; j < 4; ++j) {
    int r = rr + j * 16;
    float4 v = *(const float4*)&src[(size_t)(tr * 64 + r) * C + tc * 64 + c4];
    *(float4*)&t[r][c4] = v;
  }
  __syncthreads();
  int cc = tid >> 4, r4 = (tid & 15) * 4;
#pragma unroll
  for (int j = 0; j < 4; ++j) {
    int c = cc + j * 16;
    uint16_t ov[4];
    ov[0] = f2bf(t[r4 + 0][c]); ov[1] = f2bf(t[r4 + 1][c]);
    ov[2] = f2bf(t[r4 + 2][c]); ov[3] = f2bf(t[r4 + 3][c]);
    *(uint2*)&dst[(size_t)(tc * 64 + c) * R + tr * 64 + r4] = *(const uint2*)ov;
  }
}

// ---------------- GEMM: C[M][N] = A[M][K](bf16) * BT[N][K](bf16) + bias ----------------
template <bool OUT_BF16>
__global__ __launch_bounds__(256) void k_gemm(
    const uint16_t* __restrict__ A0, const uint16_t* __restrict__ B0,
    const float* __restrict__ bias0, void* __restrict__ C0,
    const uint16_t* __restrict__ A1, const uint16_t* __restrict__ B1,
    const float* __restrict__ bias1, void* __restrict__ C1,
    int seg0_tiles, int N, int K) {
  __shared__ __align__(16) uint16_t At[128 * 32];
  __shared__ __align__(16) uint16_t Bt[128 * 32];
  int bn = blockIdx.x, bm = blockIdx.y;
  const uint16_t* A; const uint16_t* B; const float* bias; void* C; int mrow;
  if (bm < seg0_tiles) { A = A0; B = B0; bias = bias0; C = C0; mrow = bm * 128; }
  else { A = A1; B = B1; bias = bias1; C = C1; mrow = (bm - seg0_tiles) * 128; }
  int tid = threadIdx.x, lane = tid & 63, w = tid >> 6;
  int g = lane >> 4, li = lane & 15;
  int wm = w >> 1, wn = w & 1;
  f32x4 acc[4][4] = {};
  for (int kt = 0; kt < K; kt += 32) {
#pragma unroll
    for (int j = 0; j < 2; ++j) {
      int ci = (w * 2 + j) * 64 + lane;
      int row = ci >> 2, c = ci & 3;
      async_cp16(A + (size_t)(mrow + row) * K + kt + 8 * c, (char*)At + (w * 2 + j) * 1024);
    }
#pragma unroll
    for (int j = 0; j < 2; ++j) {
      int ci = (w * 2 + j) * 64 + lane;
      int row = ci >> 2, c = ci & 3;
      async_cp16(B + (size_t)(bn * 128 + row) * K + kt + 8 * c, (char*)Bt + (w * 2 + j) * 1024);
    }
    __syncthreads();
    bf16x8 af[4], bfv[4];
#pragma unroll
    for (int mi = 0; mi < 4; ++mi) {
      int row = wm * 64 + mi * 16 + li;
      af[mi] = __builtin_bit_cast(bf16x8, *(const u32x4*)((const char*)At + row * 64 + g * 16));
    }
#pragma unroll
    for (int ni = 0; ni < 4; ++ni) {
      int row = wn * 64 + ni * 16 + li;
      bfv[ni] = __builtin_bit_cast(bf16x8, *(const u32x4*)((const char*)Bt + row * 64 + g * 16));
    }
#pragma unroll
    for (int mi = 0; mi < 4; ++mi)
#pragma unroll
      for (int ni = 0; ni < 4; ++ni)
        acc[mi][ni] = __builtin_amdgcn_mfma_f32_16x16x32_bf16(af[mi], bfv[ni], acc[mi][ni], 0, 0, 0);
    __syncthreads();
  }
#pragma unroll
  for (int mi = 0; mi < 4; ++mi) {
#pragma unroll
    for (int ni = 0; ni < 4; ++ni) {
      int col = bn * 128 + wn * 64 + ni * 16 + li;
      float bv = bias ? bias[col] : 0.0f;
#pragma unroll
      for (int i = 0; i < 4; ++i) {
        int r = mrow + wm * 64 + mi * 16 + 4 * g + i;
        float v = acc[mi][ni][i] + bv;
        if (OUT_BF16) ((uint16_t*)C)[(size_t)r * N + col] = f2bf(v);
        else          ((float*)C)[(size_t)r * N + col] = v;
      }
    }
  }
}

// ---------------- postprocess: rmsnorm + rope + scale*log2e; Q,K [H][S][D], V^T [H][D][S] ----------------
__global__ __launch_bounds__(256) void k_post(
    const uint16_t* __restrict__ qkv_img, const uint16_t* __restrict__ qkv_txt,
    const float* __restrict__ fcos, const float* __restrict__ fsin,
    const float* __restrict__ wq, const float* __restrict__ wk,
    const float* __restrict__ waq, const float* __restrict__ wak,
    uint16_t* __restrict__ Qo, uint16_t* __restrict__ Ko, uint16_t* __restrict__ VTo) {
  int s = blockIdx.x;
  const uint16_t* row = (s < S_TXT) ? qkv_txt + (size_t)s * N_QKV
                                    : qkv_img + (size_t)(s - S_TXT) * N_QKV;
  const float* wqp = (s < S_TXT) ? waq : wq;
  const float* wkp = (s < S_TXT) ? wak : wk;
  int tid = threadIdx.x, lane = tid & 63, w = tid >> 6;
  int h = w * 4 + (lane >> 4);
  int d0 = (lane & 15) * 8;
  float cs[8], sn[8];
#pragma unroll
  for (int j = 0; j < 8; ++j) {
    cs[j] = fcos[s * HD + d0 + j];
    sn[j] = fsin[s * HD + d0 + j];
  }
#pragma unroll
  for (int part = 0; part < 2; ++part) {  // 0 = Q, 1 = K
    const uint16_t* src = row + part * INNER + h * HD + d0;
    u32x4 raw = *(const u32x4*)src;
    const uint16_t* rp = (const uint16_t*)&raw;
    float x[8], ss = 0.f;
#pragma unroll
    for (int j = 0; j < 8; ++j) { x[j] = bf2f(rp[j]); ss += x[j] * x[j]; }
    ss += __shfl_xor(ss, 1); ss += __shfl_xor(ss, 2);
    ss += __shfl_xor(ss, 4); ss += __shfl_xor(ss, 8);
    float rn = rsqrtf(ss * (1.0f / HD) + ATT_EPS);
    const float* wp = part ? wkp : wqp;
#pragma unroll
    for (int j = 0; j < 8; ++j) x[j] = x[j] * rn * wp[d0 + j];
    float y[8];
#pragma unroll
    for (int j = 0; j < 8; j += 2) {
      y[j]     = x[j] * cs[j] - x[j + 1] * sn[j];
      y[j + 1] = x[j + 1] * cs[j + 1] + x[j] * sn[j + 1];
    }
    float sc = part ? 1.0f : (ATT_SCALE * LOG2E);
    uint16_t ov[8];
#pragma unroll
    for (int j = 0; j < 8; ++j) ov[j] = f2bf(y[j] * sc);
    uint16_t* dst = (part ? Ko : Qo) + ((size_t)h * S_ALL + s) * HD + d0;
    *(u32x4*)dst = *(const u32x4*)ov;
  }
  {  // V -> V^T scatter
    u32x4 raw = *(const u32x4*)(row + 2 * INNER + h * HD + d0);
    const uint16_t* rp = (const uint16_t*)&raw;
#pragma unroll
    for (int j = 0; j < 8; ++j)
      VTo[((size_t)h * HD + d0 + j) * S_ALL + s] = rp[j];
  }
}

// ---------------- attention ----------------
// 4 waves: qhalf = w&1 (32 q rows), khalf = w>>1 (32 keys of each 64-key tile).
// Fixed-max softmax (scores pre-scaled by log2e, bound 16.5). KV double-buffered,
// one barrier per tile, prefetch waited after compute.
__global__ __launch_bounds__(256, 2) void k_attn(
    const uint16_t* __restrict__ Qg, const uint16_t* __restrict__ Kg,
    const uint16_t* __restrict__ VTg, uint16_t* __restrict__ Og) {
  __shared__ __align__(16) char kvbuf[65536];   // Kt[2]:0..32K, Vt[2]:32K..64K; oLDS overlay at end
  __shared__ __align__(16) uint16_t Pl[4][32 * 40];
  __shared__ float lsumLDS[4][32];

  int b0 = blockIdx.x;
  int bid = (b0 & 7) * (HEADS * NT / 8) + (b0 >> 3);  // XCD-chunked: 2 heads per XCD
  int h = bid / NT, qt = bid % NT;
  int tid = threadIdx.x, lane = tid & 63, w = tid >> 6;
  int g = lane >> 4, li = lane & 15;
  int qhalf = w & 1, khalf = w >> 1;

  const uint16_t* Kh = Kg + (size_t)h * S_ALL * HD;
  const uint16_t* Vh = VTg + (size_t)h * HD * S_ALL;

  // Q fragments (32 rows per wave)
  bf16x8 qf[2][4];
#pragma unroll
  for (int q2 = 0; q2 < 2; ++q2) {
    int qrow = qt * 64 + qhalf * 32 + q2 * 16 + li;
    const uint16_t* qp = Qg + ((size_t)h * S_ALL + qrow) * HD;
#pragma unroll
    for (int kc = 0; kc < 4; ++kc)
      qf[q2][kc] = __builtin_bit_cast(bf16x8, *(const u32x4*)(qp + kc * 32 + g * 8));
  }
  f32x4 o[2][8] = {};
  float lsum[2][4] = {};

  // stage a 64-key tile (K: [64][128] swizzled chunk^=(row&15); V^T: [128][64] chunk^=(row&7))
  auto stage = [&](int t, int buf) {
    char* KtB = kvbuf + buf * 16384;
    char* VtB = kvbuf + 32768 + buf * 16384;
#pragma unroll
    for (int j = 0; j < 4; ++j) {
      int ci = (w * 4 + j) * 64 + lane;
      int row = ci >> 4, cc = (ci & 15) ^ (row & 15);
      async_cp16(Kh + (size_t)(t * 64 + row) * HD + 8 * cc, KtB + (w * 4 + j) * 1024);
    }
#pragma unroll
    for (int j = 0; j < 4; ++j) {
      int ci = (w * 4 + j) * 64 + lane;
      int row = ci >> 3, cc = (ci & 7) ^ (row & 7);
      async_cp16(Vh + (size_t)row * S_ALL + t * 64 + 8 * cc, VtB + (w * 4 + j) * 1024);
    }
  };

  stage(0, 0);
  asm volatile("s_waitcnt vmcnt(0)" ::: "memory");
  __builtin_amdgcn_s_barrier();

  for (int t = 0; t < NT; ++t) {
    int cur = t & 1;
    if (t + 1 < NT) stage(t + 1, cur ^ 1);
    const char* KtC = kvbuf + cur * 16384;
    const char* VtC = kvbuf + 32768 + cur * 16384;

    // QK^T: 32q x 32k per wave; C seeded with -MBOUND so exp2(sc) is the prob numerator
    f32x4 sc[2][2];
#pragma unroll
    for (int q2 = 0; q2 < 2; ++q2)
#pragma unroll
      for (int kb = 0; kb < 2; ++kb)
        sc[q2][kb] = (f32x4){-MBOUND, -MBOUND, -MBOUND, -MBOUND};
    __builtin_amdgcn_s_setprio(1);
#pragma unroll
    for (int kb = 0; kb < 2; ++kb) {
      int key = khalf * 32 + kb * 16 + li;
#pragma unroll
      for (int kc = 0; kc < 4; ++kc) {
        int chunk = (4 * kc + g) ^ (key & 15);
        bf16x8 kf = __builtin_bit_cast(bf16x8, *(const u32x4*)(KtC + key * 256 + chunk * 16));
        sc[0][kb] = __builtin_amdgcn_mfma_f32_16x16x32_bf16(qf[0][kc], kf, sc[0][kb], 0, 0, 0);
        sc[1][kb] = __builtin_amdgcn_mfma_f32_16x16x32_bf16(qf[1][kc], kf, sc[1][kb], 0, 0, 0);
      }
    }
    __builtin_amdgcn_s_setprio(0);

    // fixed-max softmax: p = exp2(sc), accumulate lsum, write P to per-wave LDS
    uint16_t* pw = &Pl[w][0];
#pragma unroll
    for (int q2 = 0; q2 < 2; ++q2)
#pragma unroll
      for (int i = 0; i < 4; ++i) {
        float p0 = fexp2(sc[q2][0][i]);
        float p1 = fexp2(sc[q2][1][i]);
        lsum[q2][i] += p0 + p1;
        int r = (q2 * 16 + 4 * g + i) * 40;
        pw[r + li] = f2bf(p0);
        pw[r + 16 + li] = f2bf(p1);
      }

    // PV: o[q2][db] += P[q2] * V^T rows
    bf16x8 pf[2];
#pragma unroll
    for (int q2 = 0; q2 < 2; ++q2)
      pf[q2] = __builtin_bit_cast(bf16x8,
          *(const u32x4*)((const char*)pw + (q2 * 16 + li) * 80 + g * 16));
    __builtin_amdgcn_s_setprio(1);
#pragma unroll
    for (int db = 0; db < 8; ++db) {
      int vrow = db * 16 + li;
      int chunk = (khalf * 4 + g) ^ (vrow & 7);
      bf16x8 vf = __builtin_bit_cast(bf16x8, *(const u32x4*)(VtC + vrow * 128 + chunk * 16));
      o[0][db] = __builtin_amdgcn_mfma_f32_16x16x32_bf16(pf[0], vf, o[0][db], 0, 0, 0);
      o[1][db] = __builtin_amdgcn_mfma_f32_16x16x32_bf16(pf[1], vf, o[1][db], 0, 0, 0);
    }
    __builtin_amdgcn_s_setprio(0);

    asm volatile("s_waitcnt vmcnt(0)" ::: "memory");  // prefetched tile landed (hidden under compute)
    __builtin_amdgcn_s_barrier();
  }

  // final: reduce lsum over key-lanes, publish partials, cross-wave combine
#pragma unroll
  for (int q2 = 0; q2 < 2; ++q2)
#pragma unroll
    for (int i = 0; i < 4; ++i) {
      float v = lsum[q2][i];
      v += __shfl_xor(v, 1); v += __shfl_xor(v, 2);
      v += __shfl_xor(v, 4); v += __shfl_xor(v, 8);
      lsum[q2][i] = v;
    }
  if (li == 0) {
#pragma unroll
    for (int q2 = 0; q2 < 2; ++q2)
#pragma unroll
      for (int i = 0; i < 4; ++i)
        lsumLDS[w][q2 * 16 + 4 * g + i] = lsum[q2][i];
  }
  float* oLDS = (float*)kvbuf;  // [2 qhalf][128 d][36 pad] fp32 = 36KB, overlays dead KV bufs
  if (khalf == 1) {
#pragma unroll
    for (int q2 = 0; q2 < 2; ++q2)
#pragma unroll
      for (int db = 0; db < 8; ++db) {
        int d = db * 16 + li;
        *(f32x4*)&oLDS[(size_t)qhalf * 4608 + d * 36 + q2 * 16 + 4 * g] = o[q2][db];
      }
  }
  __syncthreads();
  if (khalf == 0) {
    float inv[2][4];
#pragma unroll
    for (int q2 = 0; q2 < 2; ++q2)
#pragma unroll
      for (int i = 0; i < 4; ++i)
        inv[q2][i] = 1.0f / (lsum[q2][i] + lsumLDS[w + 2][q2 * 16 + 4 * g + i]);
#pragma unroll
    for (int q2 = 0; q2 < 2; ++q2)
#pragma unroll
      for (int db = 0; db < 8; ++db) {
        int d = db * 16 + li;
        f32x4 part = *(const f32x4*)&oLDS[(size_t)qhalf * 4608 + d * 36 + q2 * 16 + 4 * g];
        f32x4 ot = o[q2][db] + part;
#pragma unroll
        for (int i = 0; i < 4; ++i) {
          int qrow = qt * 64 + qhalf * 32 + q2 * 16 + 4 * g + i;
          Og[(size_t)qrow * INNER + h * HD + d] = f2bf(ot[i] * inv[q2][i]);
        }
      }
  }
}

// ---------------- launch ----------------
extern "C" void kernel_launch(void* const* d_in, const int* in_sizes, int n_in,
                              void* d_out, int out_size, void* d_ws, size_t ws_size,
                              hipStream_t stream) {
  const float* hidden = (const float*)d_in[0];
  const float* enc    = (const float*)d_in[1];
  const float* fcos   = (const float*)d_in[2];
  const float* fsin   = (const float*)d_in[3];
  const float* Wqkv   = (const float*)d_in[4];
  const float* Wqkva  = (const float*)d_in[5];
  const float* bqkva  = (const float*)d_in[6];
  const float* nqw    = (const float*)d_in[7];
  const float* nkw    = (const float*)d_in[8];
  const float* naqw   = (const float*)d_in[9];
  const float* nakw   = (const float*)d_in[10];
  const float* Wout   = (const float*)d_in[11];
  const float* bout   = (const float*)d_in[12];
  const float* Wadd   = (const float*)d_in[13];
  const float* badd   = (const float*)d_in[14];
  float* out_img = (float*)d_out;
  float* out_enc = (float*)d_out + (size_t)S_IMG * DMODEL;

  char* ws = (char*)d_ws;
  size_t off = 0;
  auto alloc = [&](size_t bytes) {
    char* p = ws + off;
    off += (bytes + 255) & ~(size_t)255;
    return p;
  };
  uint16_t* hs_bf   = (uint16_t*)alloc((size_t)S_IMG * DMODEL * 2);
  uint16_t* enc_bf  = (uint16_t*)alloc((size_t)S_TXT * DMODEL * 2);
  char*     wqkv_base = alloc((size_t)N_QKV * DMODEL * 2 * 2);  // WqkvT + WqkvaT (reused later)
  uint16_t* WqkvT   = (uint16_t*)wqkv_base;
  uint16_t* WqkvaT  = (uint16_t*)(wqkv_base + (size_t)N_QKV * DMODEL * 2);
  uint16_t* WoutT   = (uint16_t*)alloc((size_t)DMODEL * INNER * 2);
  uint16_t* WaddT   = (uint16_t*)alloc((size_t)DMODEL * INNER * 2);
  uint16_t* qkv_img = (uint16_t*)alloc((size_t)S_IMG * N_QKV * 2);
  uint16_t* qkv_txt = (uint16_t*)alloc((size_t)S_TXT * N_QKV * 2);
  // overlay Q/K/VT/attn on the Wqkv(T) region (dead after qkv GEMM): 37.8MB < 50.3MB
  uint16_t* Qb   = (uint16_t*)wqkv_base;
  uint16_t* Kb   = Qb + (size_t)HEADS * S_ALL * HD;
  uint16_t* VTb  = Kb + (size_t)HEADS * S_ALL * HD;
  uint16_t* attn = VTb + (size_t)HEADS * S_ALL * HD;

  k_cvt<<<1024, 256, 0, stream>>>(hidden, hs_bf, S_IMG * DMODEL / 4);
  k_cvt<<<256, 256, 0, stream>>>(enc, enc_bf, S_TXT * DMODEL / 4);
  k_cvt_t<<<(DMODEL / 64) * (N_QKV / 64), 256, 0, stream>>>(Wqkv, WqkvT, DMODEL, N_QKV);
  k_cvt_t<<<(DMODEL / 64) * (N_QKV / 64), 256, 0, stream>>>(Wqkva, WqkvaT, DMODEL, N_QKV);
  k_cvt_t<<<(INNER / 64) * (DMODEL / 64), 256, 0, stream>>>(Wout, WoutT, INNER, DMODEL);
  k_cvt_t<<<(INNER / 64) * (DMODEL / 64), 256, 0, stream>>>(Wadd, WaddT, INNER, DMODEL);

  dim3 gq(N_QKV / 128, (S_TXT + S_IMG) / 128);
  k_gemm<true><<<gq, 256, 0, stream>>>(enc_bf, WqkvaT, bqkva, qkv_txt,
                                       hs_bf, WqkvT, nullptr, qkv_img,
                                       S_TXT / 128, N_QKV, DMODEL);

  k_post<<<S_ALL, 256, 0, stream>>>(qkv_img, qkv_txt, fcos, fsin,
                                    nqw, nkw, naqw, nakw, Qb, Kb, VTb);

  k_attn<<<HEADS * NT, 256, 0, stream>>>(Qb, Kb, VTb, attn);

  dim3 go(DMODEL / 128, S_ALL / 128);
  k_gemm<false><<<go, 256, 0, stream>>>(attn, WaddT, badd, out_enc,
                                        attn + (size_t)S_TXT * INNER, WoutT, bout, out_img,
                                        S_TXT / 128, DMODEL, DMODEL);
}

// Round 3
// 281.365 us; speedup vs baseline: 1.3220x; 1.2153x over previous
//
#include <hip/hip_runtime.h>
#include <stdint.h>

#define HEADS 16
#define HD 128
#define S_TXT 256
#define S_IMG 2048
#define S_ALL 2304
#define DMODEL 2048
#define N_QKV 6144
#define INNER 2048
#define ATT_EPS 1e-5f
#define ATT_SCALE 0.08838834764831845f
#define LOG2E 1.4426950408889634f
#define MBOUND 16.5f
#define NT (S_ALL / 64)

typedef __attribute__((ext_vector_type(8))) __bf16 bf16x8;
typedef __attribute__((ext_vector_type(4))) float f32x4;
typedef __attribute__((ext_vector_type(4))) uint32_t u32x4;

__device__ __forceinline__ uint16_t f2bf(float f) {
  union { float f; uint32_t u; } v; v.f = f;
  uint32_t r = (v.u + 0x7FFF + ((v.u >> 16) & 1)) >> 16;
  return (uint16_t)r;
}
__device__ __forceinline__ float bf2f(uint16_t h) {
  union { float f; uint32_t u; } v; v.u = ((uint32_t)h) << 16;
  return v.f;
}
__device__ __forceinline__ float fexp2(float x) {
#if __has_builtin(__builtin_amdgcn_exp2f)
  return __builtin_amdgcn_exp2f(x);
#else
  return __expf(x * 0.69314718055994531f);
#endif
}

// async global->LDS, 16B per lane; lds ptr is wave-uniform base (HW adds lane*16)
__device__ __forceinline__ void async_cp16(const void* g, void* l) {
  __builtin_amdgcn_global_load_lds(
      (const __attribute__((address_space(1))) void*)g,
      (__attribute__((address_space(3))) void*)l, 16, 0, 0);
}

// ---------------- converts ----------------
__global__ __launch_bounds__(256) void k_cvt(const float* __restrict__ src,
                                             uint16_t* __restrict__ dst, int n4) {
  int i = blockIdx.x * 256 + threadIdx.x;
  int stride = gridDim.x * 256;
  for (; i < n4; i += stride) {
    float4 v = ((const float4*)src)[i];
    uint16_t o[4];
    o[0] = f2bf(v.x); o[1] = f2bf(v.y); o[2] = f2bf(v.z); o[3] = f2bf(v.w);
    ((uint2*)dst)[i] = *(const uint2*)o;
  }
}

// dst[C][R] = bf16(src[R][C]); 64x64 tiles, vectorized (float4 in, uint2 out)
__global__ __launch_bounds__(256) void k_cvt_t(const float* __restrict__ src,
                                               uint16_t* __restrict__ dst, int R, int C) {
  __shared__ float t[64][68];
  int ntr = R >> 6;
  int tr = blockIdx.x % ntr, tc = blockIdx.x / ntr;
  int tid = threadIdx.x;
  int rr = tid >> 4, c4 = (tid & 15) * 4;
#pragma unroll
  for (int j = 0; j < 4; ++j) {
    int r = rr + j * 16;
    float4 v = *(const float4*)&src[(size_t)(tr * 64 + r) * C + tc * 64 + c4];
    *(float4*)&t[r][c4] = v;
  }
  __syncthreads();
  int cc = tid >> 4, r4 = (tid & 15) * 4;
#pragma unroll
  for (int j = 0; j < 4; ++j) {
    int c = cc + j * 16;
    uint16_t ov[4];
    ov[0] = f2bf(t[r4 + 0][c]); ov[1] = f2bf(t[r4 + 1][c]);
    ov[2] = f2bf(t[r4 + 2][c]); ov[3] = f2bf(t[r4 + 3][c]);
    *(uint2*)&dst[(size_t)(tc * 64 + c) * R + tr * 64 + r4] = *(const uint2*)ov;
  }
}

// ---------------- deep-pipelined GEMM ----------------
// C[M][N] = A[M][K](bf16) * BT[N][K](bf16) + bias.  BM=256, BN=128, BK=64.
// 8 waves (4M x 2N, 64x64 per wave). Triple-buffered LDS (144KB), counted
// vmcnt(6) gating (T4), XOR-swizzled tiles (T2, both-sides via pre-swizzled
// global source), setprio around MFMA (T5). One barrier per K-tile.
template <bool OUT_BF16>
__global__ __launch_bounds__(512, 1) void k_gemm2(
    const uint16_t* __restrict__ A0, const uint16_t* __restrict__ B0,
    const float* __restrict__ bias0, void* __restrict__ C0,
    const uint16_t* __restrict__ A1, const uint16_t* __restrict__ B1,
    const float* __restrict__ bias1, void* __restrict__ C1,
    int seg0_tiles, int N, int K) {
  __shared__ __align__(16) char lds[3 * 49152];  // per buf: A 32KB + B 16KB
  int bn = blockIdx.x, bm = blockIdx.y;
  const uint16_t* A; const uint16_t* B; const float* bias; void* C; int mrow;
  if (bm < seg0_tiles) { A = A0; B = B0; bias = bias0; C = C0; mrow = bm * 256; }
  else { A = A1; B = B1; bias = bias1; C = C1; mrow = (bm - seg0_tiles) * 256; }
  int tid = threadIdx.x, lane = tid & 63, w = tid >> 6;
  int g = lane >> 4, li = lane & 15;
  int wm = w >> 1, wn = w & 1;  // wm 0..3 (64-row strip), wn 0..1 (64-col strip)
  const int NKI = K / 64;

  int rowin = lane >> 3;                 // row within 8-row region
  int csrc = (lane & 7) ^ rowin;         // pre-swizzled source chunk (involution)

  auto stage = [&](int t, char* buf) {
    int kt = t * 64;
    // A tile: 256 rows x 128B, 32 regions of 1KB; this wave: regions w*4..w*4+3
#pragma unroll
    for (int j = 0; j < 4; ++j) {
      int r = w * 4 + j;
      int tr = r * 8 + rowin;
      async_cp16(A + (size_t)(mrow + tr) * K + kt + 8 * csrc, buf + r * 1024);
    }
    // B tile: 128 rows x 128B, 16 regions; this wave: w*2, w*2+1
#pragma unroll
    for (int j = 0; j < 2; ++j) {
      int r = w * 2 + j;
      int tr = r * 8 + rowin;
      async_cp16(B + (size_t)(bn * 128 + tr) * K + kt + 8 * csrc, buf + 32768 + r * 1024);
    }
  };

  f32x4 acc[4][4] = {};

  stage(0, lds);
  stage(1, lds + 49152);
  asm volatile("s_waitcnt vmcnt(6)" ::: "memory");  // tile 0 landed; tile 1 in flight
  __builtin_amdgcn_s_barrier();
  asm volatile("" ::: "memory");

  int cbuf = 0, sbuf = 2;
  for (int t = 0; t < NKI; ++t) {
    const char* cur = lds + cbuf * 49152;
    if (t + 2 < NKI) stage(t + 2, lds + sbuf * 49152);

    bf16x8 af[2][4], bfv[2][4];
#pragma unroll
    for (int kk = 0; kk < 2; ++kk) {
#pragma unroll
      for (int mi = 0; mi < 4; ++mi) {
        int row = wm * 64 + mi * 16 + li;
        int ch = (kk * 4 + g) ^ (row & 7);
        af[kk][mi] = __builtin_bit_cast(bf16x8, *(const u32x4*)(cur + row * 128 + ch * 16));
      }
#pragma unroll
      for (int ni = 0; ni < 4; ++ni) {
        int row = wn * 64 + ni * 16 + li;
        int ch = (kk * 4 + g) ^ (row & 7);
        bfv[kk][ni] = __builtin_bit_cast(bf16x8, *(const u32x4*)(cur + 32768 + row * 128 + ch * 16));
      }
    }
    __builtin_amdgcn_s_setprio(1);
#pragma unroll
    for (int kk = 0; kk < 2; ++kk)
#pragma unroll
      for (int mi = 0; mi < 4; ++mi)
#pragma unroll
        for (int ni = 0; ni < 4; ++ni)
          acc[mi][ni] = __builtin_amdgcn_mfma_f32_16x16x32_bf16(af[kk][mi], bfv[kk][ni], acc[mi][ni], 0, 0, 0);
    __builtin_amdgcn_s_setprio(0);

    if (t + 1 < NKI) {
      if (t + 2 < NKI) asm volatile("s_waitcnt vmcnt(6)" ::: "memory");  // tile t+1 landed
      else             asm volatile("s_waitcnt vmcnt(0)" ::: "memory");
      __builtin_amdgcn_s_barrier();
      asm volatile("" ::: "memory");
    }
    cbuf = (cbuf + 1 == 3) ? 0 : cbuf + 1;
    sbuf = (sbuf + 1 == 3) ? 0 : sbuf + 1;
  }

  // epilogue: C row = mrow + wm*64 + mi*16 + 4g + i, col = bn*128 + wn*64 + ni*16 + li
#pragma unroll
  for (int mi = 0; mi < 4; ++mi) {
#pragma unroll
    for (int ni = 0; ni < 4; ++ni) {
      int col = bn * 128 + wn * 64 + ni * 16 + li;
      float bv = bias ? bias[col] : 0.0f;
#pragma unroll
      for (int i = 0; i < 4; ++i) {
        int r = mrow + wm * 64 + mi * 16 + 4 * g + i;
        float v = acc[mi][ni][i] + bv;
        if (OUT_BF16) ((uint16_t*)C)[(size_t)r * N + col] = f2bf(v);
        else          ((float*)C)[(size_t)r * N + col] = v;
      }
    }
  }
}

// ---------------- postprocess: rmsnorm + rope + scale*log2e; Q,K [H][S][D], V^T [H][D][S] ----------------
__global__ __launch_bounds__(256) void k_post(
    const uint16_t* __restrict__ qkv_img, const uint16_t* __restrict__ qkv_txt,
    const float* __restrict__ fcos, const float* __restrict__ fsin,
    const float* __restrict__ wq, const float* __restrict__ wk,
    const float* __restrict__ waq, const float* __restrict__ wak,
    uint16_t* __restrict__ Qo, uint16_t* __restrict__ Ko, uint16_t* __restrict__ VTo) {
  int s = blockIdx.x;
  const uint16_t* row = (s < S_TXT) ? qkv_txt + (size_t)s * N_QKV
                                    : qkv_img + (size_t)(s - S_TXT) * N_QKV;
  const float* wqp = (s < S_TXT) ? waq : wq;
  const float* wkp = (s < S_TXT) ? wak : wk;
  int tid = threadIdx.x, lane = tid & 63, w = tid >> 6;
  int h = w * 4 + (lane >> 4);
  int d0 = (lane & 15) * 8;
  float cs[8], sn[8];
#pragma unroll
  for (int j = 0; j < 8; ++j) {
    cs[j] = fcos[s * HD + d0 + j];
    sn[j] = fsin[s * HD + d0 + j];
  }
#pragma unroll
  for (int part = 0; part < 2; ++part) {  // 0 = Q, 1 = K
    const uint16_t* src = row + part * INNER + h * HD + d0;
    u32x4 raw = *(const u32x4*)src;
    const uint16_t* rp = (const uint16_t*)&raw;
    float x[8], ss = 0.f;
#pragma unroll
    for (int j = 0; j < 8; ++j) { x[j] = bf2f(rp[j]); ss += x[j] * x[j]; }
    ss += __shfl_xor(ss, 1); ss += __shfl_xor(ss, 2);
    ss += __shfl_xor(ss, 4); ss += __shfl_xor(ss, 8);
    float rn = rsqrtf(ss * (1.0f / HD) + ATT_EPS);
    const float* wp = part ? wkp : wqp;
#pragma unroll
    for (int j = 0; j < 8; ++j) x[j] = x[j] * rn * wp[d0 + j];
    float y[8];
#pragma unroll
    for (int j = 0; j < 8; j += 2) {
      y[j]     = x[j] * cs[j] - x[j + 1] * sn[j];
      y[j + 1] = x[j + 1] * cs[j + 1] + x[j] * sn[j + 1];
    }
    float sc = part ? 1.0f : (ATT_SCALE * LOG2E);
    uint16_t ov[8];
#pragma unroll
    for (int j = 0; j < 8; ++j) ov[j] = f2bf(y[j] * sc);
    uint16_t* dst = (part ? Ko : Qo) + ((size_t)h * S_ALL + s) * HD + d0;
    *(u32x4*)dst = *(const u32x4*)ov;
  }
  {  // V -> V^T scatter
    u32x4 raw = *(const u32x4*)(row + 2 * INNER + h * HD + d0);
    const uint16_t* rp = (const uint16_t*)&raw;
#pragma unroll
    for (int j = 0; j < 8; ++j)
      VTo[((size_t)h * HD + d0 + j) * S_ALL + s] = rp[j];
  }
}

// ---------------- attention ----------------
// 4 waves: qhalf = w&1 (32 q rows), khalf = w>>1 (32 keys of each 64-key tile).
// Fixed-max softmax (scores pre-scaled by log2e, bound 16.5). KV double-buffered,
// one barrier per tile, prefetch waited after compute.
__global__ __launch_bounds__(256, 2) void k_attn(
    const uint16_t* __restrict__ Qg, const uint16_t* __restrict__ Kg,
    const uint16_t* __restrict__ VTg, uint16_t* __restrict__ Og) {
  __shared__ __align__(16) char kvbuf[65536];   // Kt[2]:0..32K, Vt[2]:32K..64K; oLDS overlay at end
  __shared__ __align__(16) uint16_t Pl[4][32 * 40];
  __shared__ float lsumLDS[4][32];

  int b0 = blockIdx.x;
  int bid = (b0 & 7) * (HEADS * NT / 8) + (b0 >> 3);  // XCD-chunked: 2 heads per XCD
  int h = bid / NT, qt = bid % NT;
  int tid = threadIdx.x, lane = tid & 63, w = tid >> 6;
  int g = lane >> 4, li = lane & 15;
  int qhalf = w & 1, khalf = w >> 1;

  const uint16_t* Kh = Kg + (size_t)h * S_ALL * HD;
  const uint16_t* Vh = VTg + (size_t)h * HD * S_ALL;

  bf16x8 qf[2][4];
#pragma unroll
  for (int q2 = 0; q2 < 2; ++q2) {
    int qrow = qt * 64 + qhalf * 32 + q2 * 16 + li;
    const uint16_t* qp = Qg + ((size_t)h * S_ALL + qrow) * HD;
#pragma unroll
    for (int kc = 0; kc < 4; ++kc)
      qf[q2][kc] = __builtin_bit_cast(bf16x8, *(const u32x4*)(qp + kc * 32 + g * 8));
  }
  f32x4 o[2][8] = {};
  float lsum[2][4] = {};

  auto stage = [&](int t, int buf) {
    char* KtB = kvbuf + buf * 16384;
    char* VtB = kvbuf + 32768 + buf * 16384;
#pragma unroll
    for (int j = 0; j < 4; ++j) {
      int ci = (w * 4 + j) * 64 + lane;
      int row = ci >> 4, cc = (ci & 15) ^ (row & 15);
      async_cp16(Kh + (size_t)(t * 64 + row) * HD + 8 * cc, KtB + (w * 4 + j) * 1024);
    }
#pragma unroll
    for (int j = 0; j < 4; ++j) {
      int ci = (w * 4 + j) * 64 + lane;
      int row = ci >> 3, cc = (ci & 7) ^ (row & 7);
      async_cp16(Vh + (size_t)row * S_ALL + t * 64 + 8 * cc, VtB + (w * 4 + j) * 1024);
    }
  };

  stage(0, 0);
  asm volatile("s_waitcnt vmcnt(0)" ::: "memory");
  __builtin_amdgcn_s_barrier();

  for (int t = 0; t < NT; ++t) {
    int cur = t & 1;
    if (t + 1 < NT) stage(t + 1, cur ^ 1);
    const char* KtC = kvbuf + cur * 16384;
    const char* VtC = kvbuf + 32768 + cur * 16384;

    f32x4 sc[2][2];
#pragma unroll
    for (int q2 = 0; q2 < 2; ++q2)
#pragma unroll
      for (int kb = 0; kb < 2; ++kb)
        sc[q2][kb] = (f32x4){-MBOUND, -MBOUND, -MBOUND, -MBOUND};
    __builtin_amdgcn_s_setprio(1);
#pragma unroll
    for (int kb = 0; kb < 2; ++kb) {
      int key = khalf * 32 + kb * 16 + li;
#pragma unroll
      for (int kc = 0; kc < 4; ++kc) {
        int chunk = (4 * kc + g) ^ (key & 15);
        bf16x8 kf = __builtin_bit_cast(bf16x8, *(const u32x4*)(KtC + key * 256 + chunk * 16));
        sc[0][kb] = __builtin_amdgcn_mfma_f32_16x16x32_bf16(qf[0][kc], kf, sc[0][kb], 0, 0, 0);
        sc[1][kb] = __builtin_amdgcn_mfma_f32_16x16x32_bf16(qf[1][kc], kf, sc[1][kb], 0, 0, 0);
      }
    }
    __builtin_amdgcn_s_setprio(0);

    uint16_t* pw = &Pl[w][0];
#pragma unroll
    for (int q2 = 0; q2 < 2; ++q2)
#pragma unroll
      for (int i = 0; i < 4; ++i) {
        float p0 = fexp2(sc[q2][0][i]);
        float p1 = fexp2(sc[q2][1][i]);
        lsum[q2][i] += p0 + p1;
        int r = (q2 * 16 + 4 * g + i) * 40;
        pw[r + li] = f2bf(p0);
        pw[r + 16 + li] = f2bf(p1);
      }

    bf16x8 pf[2];
#pragma unroll
    for (int q2 = 0; q2 < 2; ++q2)
      pf[q2] = __builtin_bit_cast(bf16x8,
          *(const u32x4*)((const char*)pw + (q2 * 16 + li) * 80 + g * 16));
    __builtin_amdgcn_s_setprio(1);
#pragma unroll
    for (int db = 0; db < 8; ++db) {
      int vrow = db * 16 + li;
      int chunk = (khalf * 4 + g) ^ (vrow & 7);
      bf16x8 vf = __builtin_bit_cast(bf16x8, *(const u32x4*)(VtC + vrow * 128 + chunk * 16));
      o[0][db] = __builtin_amdgcn_mfma_f32_16x16x32_bf16(pf[0], vf, o[0][db], 0, 0, 0);
      o[1][db] = __builtin_amdgcn_mfma_f32_16x16x32_bf16(pf[1], vf, o[1][db], 0, 0, 0);
    }
    __builtin_amdgcn_s_setprio(0);

    asm volatile("s_waitcnt vmcnt(0)" ::: "memory");
    __builtin_amdgcn_s_barrier();
  }

#pragma unroll
  for (int q2 = 0; q2 < 2; ++q2)
#pragma unroll
    for (int i = 0; i < 4; ++i) {
      float v = lsum[q2][i];
      v += __shfl_xor(v, 1); v += __shfl_xor(v, 2);
      v += __shfl_xor(v, 4); v += __shfl_xor(v, 8);
      lsum[q2][i] = v;
    }
  if (li == 0) {
#pragma unroll
    for (int q2 = 0; q2 < 2; ++q2)
#pragma unroll
      for (int i = 0; i < 4; ++i)
        lsumLDS[w][q2 * 16 + 4 * g + i] = lsum[q2][i];
  }
  float* oLDS = (float*)kvbuf;  // [2 qhalf][128 d][36 pad] fp32 = 36KB, overlays dead KV bufs
  if (khalf == 1) {
#pragma unroll
    for (int q2 = 0; q2 < 2; ++q2)
#pragma unroll
      for (int db = 0; db < 8; ++db) {
        int d = db * 16 + li;
        *(f32x4*)&oLDS[(size_t)qhalf * 4608 + d * 36 + q2 * 16 + 4 * g] = o[q2][db];
      }
  }
  __syncthreads();
  if (khalf == 0) {
    float inv[2][4];
#pragma unroll
    for (int q2 = 0; q2 < 2; ++q2)
#pragma unroll
      for (int i = 0; i < 4; ++i)
        inv[q2][i] = 1.0f / (lsum[q2][i] + lsumLDS[w + 2][q2 * 16 + 4 * g + i]);
#pragma unroll
    for (int q2 = 0; q2 < 2; ++q2)
#pragma unroll
      for (int db = 0; db < 8; ++db) {
        int d = db * 16 + li;
        f32x4 part = *(const f32x4*)&oLDS[(size_t)qhalf * 4608 + d * 36 + q2 * 16 + 4 * g];
        f32x4 ot = o[q2][db] + part;
#pragma unroll
        for (int i = 0; i < 4; ++i) {
          int qrow = qt * 64 + qhalf * 32 + q2 * 16 + 4 * g + i;
          Og[(size_t)qrow * INNER + h * HD + d] = f2bf(ot[i] * inv[q2][i]);
        }
      }
  }
}

// ---------------- launch ----------------
extern "C" void kernel_launch(void* const* d_in, const int* in_sizes, int n_in,
                              void* d_out, int out_size, void* d_ws, size_t ws_size,
                              hipStream_t stream) {
  const float* hidden = (const float*)d_in[0];
  const float* enc    = (const float*)d_in[1];
  const float* fcos   = (const float*)d_in[2];
  const float* fsin   = (const float*)d_in[3];
  const float* Wqkv   = (const float*)d_in[4];
  const float* Wqkva  = (const float*)d_in[5];
  const float* bqkva  = (const float*)d_in[6];
  const float* nqw    = (const float*)d_in[7];
  const float* nkw    = (const float*)d_in[8];
  const float* naqw   = (const float*)d_in[9];
  const float* nakw   = (const float*)d_in[10];
  const float* Wout   = (const float*)d_in[11];
  const float* bout   = (const float*)d_in[12];
  const float* Wadd   = (const float*)d_in[13];
  const float* badd   = (const float*)d_in[14];
  float* out_img = (float*)d_out;
  float* out_enc = (float*)d_out + (size_t)S_IMG * DMODEL;

  char* ws = (char*)d_ws;
  size_t off = 0;
  auto alloc = [&](size_t bytes) {
    char* p = ws + off;
    off += (bytes + 255) & ~(size_t)255;
    return p;
  };
  uint16_t* hs_bf   = (uint16_t*)alloc((size_t)S_IMG * DMODEL * 2);
  uint16_t* enc_bf  = (uint16_t*)alloc((size_t)S_TXT * DMODEL * 2);
  char*     wqkv_base = alloc((size_t)N_QKV * DMODEL * 2 * 2);  // WqkvT + WqkvaT (reused later)
  uint16_t* WqkvT   = (uint16_t*)wqkv_base;
  uint16_t* WqkvaT  = (uint16_t*)(wqkv_base + (size_t)N_QKV * DMODEL * 2);
  uint16_t* WoutT   = (uint16_t*)alloc((size_t)DMODEL * INNER * 2);
  uint16_t* WaddT   = (uint16_t*)alloc((size_t)DMODEL * INNER * 2);
  uint16_t* qkv_img = (uint16_t*)alloc((size_t)S_IMG * N_QKV * 2);
  uint16_t* qkv_txt = (uint16_t*)alloc((size_t)S_TXT * N_QKV * 2);
  // overlay Q/K/VT/attn on the Wqkv(T) region (dead after qkv GEMM): 37.8MB < 50.3MB
  uint16_t* Qb   = (uint16_t*)wqkv_base;
  uint16_t* Kb   = Qb + (size_t)HEADS * S_ALL * HD;
  uint16_t* VTb  = Kb + (size_t)HEADS * S_ALL * HD;
  uint16_t* attn = VTb + (size_t)HEADS * S_ALL * HD;

  k_cvt<<<1024, 256, 0, stream>>>(hidden, hs_bf, S_IMG * DMODEL / 4);
  k_cvt<<<256, 256, 0, stream>>>(enc, enc_bf, S_TXT * DMODEL / 4);
  k_cvt_t<<<(DMODEL / 64) * (N_QKV / 64), 256, 0, stream>>>(Wqkv, WqkvT, DMODEL, N_QKV);
  k_cvt_t<<<(DMODEL / 64) * (N_QKV / 64), 256, 0, stream>>>(Wqkva, WqkvaT, DMODEL, N_QKV);
  k_cvt_t<<<(INNER / 64) * (DMODEL / 64), 256, 0, stream>>>(Wout, WoutT, INNER, DMODEL);
  k_cvt_t<<<(INNER / 64) * (DMODEL / 64), 256, 0, stream>>>(Wadd, WaddT, INNER, DMODEL);

  dim3 gq(N_QKV / 128, (S_TXT + S_IMG) / 256);
  k_gemm2<true><<<gq, 512, 0, stream>>>(enc_bf, WqkvaT, bqkva, qkv_txt,
                                        hs_bf, WqkvT, nullptr, qkv_img,
                                        1, N_QKV, DMODEL);

  k_post<<<S_ALL, 256, 0, stream>>>(qkv_img, qkv_txt, fcos, fsin,
                                    nqw, nkw, naqw, nakw, Qb, Kb, VTb);

  k_attn<<<HEADS * NT, 256, 0, stream>>>(Qb, Kb, VTb, attn);

  dim3 go(DMODEL / 128, S_ALL / 256);
  k_gemm2<false><<<go, 512, 0, stream>>>(attn, WaddT, badd, out_enc,
                                         attn + (size_t)S_TXT * INNER, WoutT, bout, out_img,
                                         1, DMODEL, DMODEL);
}

// Round 4
// 261.894 us; speedup vs baseline: 1.4202x; 1.0743x over previous
//
#include <hip/hip_runtime.h>
#include <stdint.h>

#define HEADS 16
#define HD 128
#define S_TXT 256
#define S_IMG 2048
#define S_ALL 2304
#define DMODEL 2048
#define N_QKV 6144
#define INNER 2048
#define ATT_EPS 1e-5f
#define ATT_SCALE 0.08838834764831845f
#define LOG2E 1.4426950408889634f
#define MBOUND 16.5f
#define NT32 (S_ALL / 32)

typedef __attribute__((ext_vector_type(8))) __bf16 bf16x8;
typedef __attribute__((ext_vector_type(4))) float f32x4;
typedef __attribute__((ext_vector_type(4))) uint32_t u32x4;

__device__ __forceinline__ uint16_t f2bf(float f) {
  union { float f; uint32_t u; } v; v.f = f;
  uint32_t r = (v.u + 0x7FFF + ((v.u >> 16) & 1)) >> 16;
  return (uint16_t)r;
}
__device__ __forceinline__ float bf2f(uint16_t h) {
  union { float f; uint32_t u; } v; v.u = ((uint32_t)h) << 16;
  return v.f;
}
__device__ __forceinline__ float fexp2(float x) {
#if __has_builtin(__builtin_amdgcn_exp2f)
  return __builtin_amdgcn_exp2f(x);
#else
  return __expf(x * 0.69314718055994531f);
#endif
}

// async global->LDS, 16B per lane; lds ptr is wave-uniform base (HW adds lane*16)
__device__ __forceinline__ void async_cp16(const void* g, void* l) {
  __builtin_amdgcn_global_load_lds(
      (const __attribute__((address_space(1))) void*)g,
      (__attribute__((address_space(3))) void*)l, 16, 0, 0);
}

// ---------------- converts ----------------
__global__ __launch_bounds__(256) void k_cvt(const float* __restrict__ src,
                                             uint16_t* __restrict__ dst, int n4) {
  int i = blockIdx.x * 256 + threadIdx.x;
  int stride = gridDim.x * 256;
  for (; i < n4; i += stride) {
    float4 v = ((const float4*)src)[i];
    uint16_t o[4];
    o[0] = f2bf(v.x); o[1] = f2bf(v.y); o[2] = f2bf(v.z); o[3] = f2bf(v.w);
    ((uint2*)dst)[i] = *(const uint2*)o;
  }
}

// dst[C][R] = bf16(src[R][C]); 64x64 tiles, vectorized (float4 in, uint2 out)
__global__ __launch_bounds__(256) void k_cvt_t(const float* __restrict__ src,
                                               uint16_t* __restrict__ dst, int R, int C) {
  __shared__ float t[64][68];
  int ntr = R >> 6;
  int tr = blockIdx.x % ntr, tc = blockIdx.x / ntr;
  int tid = threadIdx.x;
  int rr = tid >> 4, c4 = (tid & 15) * 4;
#pragma unroll
  for (int j = 0; j < 4; ++j) {
    int r = rr + j * 16;
    float4 v = *(const float4*)&src[(size_t)(tr * 64 + r) * C + tc * 64 + c4];
    *(float4*)&t[r][c4] = v;
  }
  __syncthreads();
  int cc = tid >> 4, r4 = (tid & 15) * 4;
#pragma unroll
  for (int j = 0; j < 4; ++j) {
    int c = cc + j * 16;
    uint16_t ov[4];
    ov[0] = f2bf(t[r4 + 0][c]); ov[1] = f2bf(t[r4 + 1][c]);
    ov[2] = f2bf(t[r4 + 2][c]); ov[3] = f2bf(t[r4 + 3][c]);
    *(uint2*)&dst[(size_t)(tc * 64 + c) * R + tr * 64 + r4] = *(const uint2*)ov;
  }
}

// ---------------- deep-pipelined GEMM ----------------
// C[M][N] = A[M][K](bf16) * BT[N][K](bf16) + bias.  BM=256, BN=128, BK=64.
// 8 waves (4M x 2N, 64x64 per wave). Triple-buffered LDS (144KB), counted
// vmcnt(6) gating (T4), XOR-swizzled tiles (T2), setprio (T5).
template <bool OUT_BF16>
__global__ __launch_bounds__(512, 1) void k_gemm2(
    const uint16_t* __restrict__ A0, const uint16_t* __restrict__ B0,
    const float* __restrict__ bias0, void* __restrict__ C0,
    const uint16_t* __restrict__ A1, const uint16_t* __restrict__ B1,
    const float* __restrict__ bias1, void* __restrict__ C1,
    int seg0_tiles, int N, int K) {
  __shared__ __align__(16) char lds[3 * 49152];  // per buf: A 32KB + B 16KB
  int bn = blockIdx.x, bm = blockIdx.y;
  const uint16_t* A; const uint16_t* B; const float* bias; void* C; int mrow;
  if (bm < seg0_tiles) { A = A0; B = B0; bias = bias0; C = C0; mrow = bm * 256; }
  else { A = A1; B = B1; bias = bias1; C = C1; mrow = (bm - seg0_tiles) * 256; }
  int tid = threadIdx.x, lane = tid & 63, w = tid >> 6;
  int g = lane >> 4, li = lane & 15;
  int wm = w >> 1, wn = w & 1;
  const int NKI = K / 64;

  int rowin = lane >> 3;
  int csrc = (lane & 7) ^ rowin;

  auto stage = [&](int t, char* buf) {
    int kt = t * 64;
#pragma unroll
    for (int j = 0; j < 4; ++j) {
      int r = w * 4 + j;
      int tr = r * 8 + rowin;
      async_cp16(A + (size_t)(mrow + tr) * K + kt + 8 * csrc, buf + r * 1024);
    }
#pragma unroll
    for (int j = 0; j < 2; ++j) {
      int r = w * 2 + j;
      int tr = r * 8 + rowin;
      async_cp16(B + (size_t)(bn * 128 + tr) * K + kt + 8 * csrc, buf + 32768 + r * 1024);
    }
  };

  f32x4 acc[4][4] = {};

  stage(0, lds);
  stage(1, lds + 49152);
  asm volatile("s_waitcnt vmcnt(6)" ::: "memory");
  __builtin_amdgcn_s_barrier();
  asm volatile("" ::: "memory");

  int cbuf = 0, sbuf = 2;
  for (int t = 0; t < NKI; ++t) {
    const char* cur = lds + cbuf * 49152;
    if (t + 2 < NKI) stage(t + 2, lds + sbuf * 49152);

    bf16x8 af[2][4], bfv[2][4];
#pragma unroll
    for (int kk = 0; kk < 2; ++kk) {
#pragma unroll
      for (int mi = 0; mi < 4; ++mi) {
        int row = wm * 64 + mi * 16 + li;
        int ch = (kk * 4 + g) ^ (row & 7);
        af[kk][mi] = __builtin_bit_cast(bf16x8, *(const u32x4*)(cur + row * 128 + ch * 16));
      }
#pragma unroll
      for (int ni = 0; ni < 4; ++ni) {
        int row = wn * 64 + ni * 16 + li;
        int ch = (kk * 4 + g) ^ (row & 7);
        bfv[kk][ni] = __builtin_bit_cast(bf16x8, *(const u32x4*)(cur + 32768 + row * 128 + ch * 16));
      }
    }
    __builtin_amdgcn_s_setprio(1);
#pragma unroll
    for (int kk = 0; kk < 2; ++kk)
#pragma unroll
      for (int mi = 0; mi < 4; ++mi)
#pragma unroll
        for (int ni = 0; ni < 4; ++ni)
          acc[mi][ni] = __builtin_amdgcn_mfma_f32_16x16x32_bf16(af[kk][mi], bfv[kk][ni], acc[mi][ni], 0, 0, 0);
    __builtin_amdgcn_s_setprio(0);

    if (t + 1 < NKI) {
      if (t + 2 < NKI) asm volatile("s_waitcnt vmcnt(6)" ::: "memory");
      else             asm volatile("s_waitcnt vmcnt(0)" ::: "memory");
      __builtin_amdgcn_s_barrier();
      asm volatile("" ::: "memory");
    }
    cbuf = (cbuf + 1 == 3) ? 0 : cbuf + 1;
    sbuf = (sbuf + 1 == 3) ? 0 : sbuf + 1;
  }

#pragma unroll
  for (int mi = 0; mi < 4; ++mi) {
#pragma unroll
    for (int ni = 0; ni < 4; ++ni) {
      int col = bn * 128 + wn * 64 + ni * 16 + li;
      float bv = bias ? bias[col] : 0.0f;
#pragma unroll
      for (int i = 0; i < 4; ++i) {
        int r = mrow + wm * 64 + mi * 16 + 4 * g + i;
        float v = acc[mi][ni][i] + bv;
        if (OUT_BF16) ((uint16_t*)C)[(size_t)r * N + col] = f2bf(v);
        else          ((float*)C)[(size_t)r * N + col] = v;
      }
    }
  }
}

// ---------------- postprocess: rmsnorm + rope + scale*log2e; Q,K [H][S][D], V^T [H][D][S] ----------------
__global__ __launch_bounds__(256) void k_post(
    const uint16_t* __restrict__ qkv_img, const uint16_t* __restrict__ qkv_txt,
    const float* __restrict__ fcos, const float* __restrict__ fsin,
    const float* __restrict__ wq, const float* __restrict__ wk,
    const float* __restrict__ waq, const float* __restrict__ wak,
    uint16_t* __restrict__ Qo, uint16_t* __restrict__ Ko, uint16_t* __restrict__ VTo) {
  int s = blockIdx.x;
  const uint16_t* row = (s < S_TXT) ? qkv_txt + (size_t)s * N_QKV
                                    : qkv_img + (size_t)(s - S_TXT) * N_QKV;
  const float* wqp = (s < S_TXT) ? waq : wq;
  const float* wkp = (s < S_TXT) ? wak : wk;
  int tid = threadIdx.x, lane = tid & 63, w = tid >> 6;
  int h = w * 4 + (lane >> 4);
  int d0 = (lane & 15) * 8;
  float cs[8], sn[8];
#pragma unroll
  for (int j = 0; j < 8; ++j) {
    cs[j] = fcos[s * HD + d0 + j];
    sn[j] = fsin[s * HD + d0 + j];
  }
#pragma unroll
  for (int part = 0; part < 2; ++part) {  // 0 = Q, 1 = K
    const uint16_t* src = row + part * INNER + h * HD + d0;
    u32x4 raw = *(const u32x4*)src;
    const uint16_t* rp = (const uint16_t*)&raw;
    float x[8], ss = 0.f;
#pragma unroll
    for (int j = 0; j < 8; ++j) { x[j] = bf2f(rp[j]); ss += x[j] * x[j]; }
    ss += __shfl_xor(ss, 1); ss += __shfl_xor(ss, 2);
    ss += __shfl_xor(ss, 4); ss += __shfl_xor(ss, 8);
    float rn = rsqrtf(ss * (1.0f / HD) + ATT_EPS);
    const float* wp = part ? wkp : wqp;
#pragma unroll
    for (int j = 0; j < 8; ++j) x[j] = x[j] * rn * wp[d0 + j];
    float y[8];
#pragma unroll
    for (int j = 0; j < 8; j += 2) {
      y[j]     = x[j] * cs[j] - x[j + 1] * sn[j];
      y[j + 1] = x[j + 1] * cs[j + 1] + x[j] * sn[j + 1];
    }
    float sc = part ? 1.0f : (ATT_SCALE * LOG2E);
    uint16_t ov[8];
#pragma unroll
    for (int j = 0; j < 8; ++j) ov[j] = f2bf(y[j] * sc);
    uint16_t* dst = (part ? Ko : Qo) + ((size_t)h * S_ALL + s) * HD + d0;
    *(u32x4*)dst = *(const u32x4*)ov;
  }
  {  // V -> V^T scatter
    u32x4 raw = *(const u32x4*)(row + 2 * INNER + h * HD + d0);
    const uint16_t* rp = (const uint16_t*)&raw;
#pragma unroll
    for (int j = 0; j < 8; ++j)
      VTo[((size_t)h * HD + d0 + j) * S_ALL + s] = rp[j];
  }
}

// ---------------- attention ----------------
// KVBLK=32, 4 waves: QK^T role (qhalf=w&1 x khalf=w>>1), PV role (qhalf x dhalf=w>>1).
// Fixed-max softmax; P cross-wave via LDS; 37.5KB LDS -> 4 blocks/CU, whole grid resident.
__global__ __launch_bounds__(256, 4) void k_attn(
    const uint16_t* __restrict__ Qg, const uint16_t* __restrict__ Kg,
    const uint16_t* __restrict__ VTg, uint16_t* __restrict__ Og) {
  __shared__ __align__(16) char Kt[2][8192];     // [32 key][128 d] bf16, chunk^=(row&15)
  __shared__ __align__(16) char Vt[2][8192];     // [128 d][32 s] bf16, linear
  __shared__ __align__(16) uint16_t Pl[2][32][40];  // [qhalf][qrow][key(+pad)]
  __shared__ float lsumLDS[2][2][32];

  int b0 = blockIdx.x;
  int bid = (b0 & 7) * (HEADS * (S_ALL / 64) / 8) + (b0 >> 3);  // XCD-chunked
  int h = bid / (S_ALL / 64), qt = bid % (S_ALL / 64);
  int tid = threadIdx.x, lane = tid & 63, w = tid >> 6;
  int g = lane >> 4, li = lane & 15;
  int qh = w & 1, kh = w >> 1;  // kh doubles as d-half in PV

  const uint16_t* Kh = Kg + (size_t)h * S_ALL * HD;
  const uint16_t* Vh = VTg + (size_t)h * HD * S_ALL;

  bf16x8 qf[2][4];
#pragma unroll
  for (int q2 = 0; q2 < 2; ++q2) {
    int qrow = qt * 64 + qh * 32 + q2 * 16 + li;
    const uint16_t* qp = Qg + ((size_t)h * S_ALL + qrow) * HD;
#pragma unroll
    for (int kc = 0; kc < 4; ++kc)
      qf[q2][kc] = __builtin_bit_cast(bf16x8, *(const u32x4*)(qp + kc * 32 + g * 8));
  }
  f32x4 o[2][4] = {};
  float lsum[2][4] = {};

  auto stage = [&](int t, int buf) {
#pragma unroll
    for (int j = 0; j < 2; ++j) {  // K tile: 512 chunks, this wave: w*128 + j*64 + lane
      int cj = w * 128 + j * 64 + lane;
      int row = cj >> 4, c = (cj & 15) ^ (row & 15);
      async_cp16(Kh + (size_t)(t * 32 + row) * HD + 8 * c, Kt[buf] + (w * 128 + j * 64) * 16);
    }
#pragma unroll
    for (int j = 0; j < 2; ++j) {  // V^T tile: rows=d, 4 chunks/row, linear
      int cj = w * 128 + j * 64 + lane;
      int row = cj >> 2, c = cj & 3;
      async_cp16(Vh + (size_t)row * S_ALL + t * 32 + 8 * c, Vt[buf] + (w * 128 + j * 64) * 16);
    }
  };

  stage(0, 0);
  asm volatile("s_waitcnt vmcnt(0)" ::: "memory");
  __builtin_amdgcn_s_barrier();
  asm volatile("" ::: "memory");

  for (int t = 0; t < NT32; ++t) {
    int cur = t & 1;
    if (t + 1 < NT32) stage(t + 1, cur ^ 1);
    const char* KtC = Kt[cur];
    const char* VtC = Vt[cur];

    // QK^T: 32q x 16k (this wave's key-half), k-contraction d=128
    f32x4 sc[2];
#pragma unroll
    for (int q2 = 0; q2 < 2; ++q2) sc[q2] = (f32x4){-MBOUND, -MBOUND, -MBOUND, -MBOUND};
    int key = kh * 16 + li;
    __builtin_amdgcn_s_setprio(1);
#pragma unroll
    for (int kc = 0; kc < 4; ++kc) {
      int chunk = (kc * 4 + g) ^ (key & 15);
      bf16x8 kf = __builtin_bit_cast(bf16x8, *(const u32x4*)(KtC + key * 256 + chunk * 16));
      sc[0] = __builtin_amdgcn_mfma_f32_16x16x32_bf16(qf[0][kc], kf, sc[0], 0, 0, 0);
      sc[1] = __builtin_amdgcn_mfma_f32_16x16x32_bf16(qf[1][kc], kf, sc[1], 0, 0, 0);
    }
    __builtin_amdgcn_s_setprio(0);

    // fixed-max softmax: p = exp2(sc); write P[qh][qrow][key]
#pragma unroll
    for (int q2 = 0; q2 < 2; ++q2)
#pragma unroll
      for (int i = 0; i < 4; ++i) {
        float p = fexp2(sc[q2][i]);
        lsum[q2][i] += p;
        Pl[qh][q2 * 16 + 4 * g + i][kh * 16 + li] = f2bf(p);
      }
    asm volatile("s_waitcnt lgkmcnt(0)" ::: "memory");  // P writes visible
    __builtin_amdgcn_s_barrier();
    asm volatile("" ::: "memory");

    // PV: 32q x 64d (this wave's d-half), k=32 keys
    bf16x8 pf[2];
#pragma unroll
    for (int q2 = 0; q2 < 2; ++q2)
      pf[q2] = __builtin_bit_cast(bf16x8,
          *(const u32x4*)((const char*)Pl[qh] + (q2 * 16 + li) * 80 + g * 16));
    __builtin_amdgcn_s_setprio(1);
#pragma unroll
    for (int db = 0; db < 4; ++db) {
      int vrow = kh * 64 + db * 16 + li;
      bf16x8 vf = __builtin_bit_cast(bf16x8, *(const u32x4*)(VtC + vrow * 64 + g * 16));
      o[0][db] = __builtin_amdgcn_mfma_f32_16x16x32_bf16(pf[0], vf, o[0][db], 0, 0, 0);
      o[1][db] = __builtin_amdgcn_mfma_f32_16x16x32_bf16(pf[1], vf, o[1][db], 0, 0, 0);
    }
    __builtin_amdgcn_s_setprio(0);

    asm volatile("s_waitcnt vmcnt(0)" ::: "memory");  // t+1 staged (hidden under compute)
    __builtin_amdgcn_s_barrier();
    asm volatile("" ::: "memory");
  }

  // lsum: reduce over 16 key-lanes, publish per k-half, combine
#pragma unroll
  for (int q2 = 0; q2 < 2; ++q2)
#pragma unroll
    for (int i = 0; i < 4; ++i) {
      float v = lsum[q2][i];
      v += __shfl_xor(v, 1); v += __shfl_xor(v, 2);
      v += __shfl_xor(v, 4); v += __shfl_xor(v, 8);
      lsum[q2][i] = v;
    }
  if (li == 0) {
#pragma unroll
    for (int q2 = 0; q2 < 2; ++q2)
#pragma unroll
      for (int i = 0; i < 4; ++i)
        lsumLDS[qh][kh][q2 * 16 + 4 * g + i] = lsum[q2][i];
  }
  __syncthreads();
#pragma unroll
  for (int q2 = 0; q2 < 2; ++q2) {
#pragma unroll
    for (int i = 0; i < 4; ++i) {
      int idx = q2 * 16 + 4 * g + i;
      float inv = 1.0f / (lsumLDS[qh][0][idx] + lsumLDS[qh][1][idx]);
      int qrow = qt * 64 + qh * 32 + idx;
#pragma unroll
      for (int db = 0; db < 4; ++db)
        Og[(size_t)qrow * INNER + h * HD + kh * 64 + db * 16 + li] = f2bf(o[q2][db][i] * inv);
    }
  }
}

// ---------------- launch ----------------
extern "C" void kernel_launch(void* const* d_in, const int* in_sizes, int n_in,
                              void* d_out, int out_size, void* d_ws, size_t ws_size,
                              hipStream_t stream) {
  const float* hidden = (const float*)d_in[0];
  const float* enc    = (const float*)d_in[1];
  const float* fcos   = (const float*)d_in[2];
  const float* fsin   = (const float*)d_in[3];
  const float* Wqkv   = (const float*)d_in[4];
  const float* Wqkva  = (const float*)d_in[5];
  const float* bqkva  = (const float*)d_in[6];
  const float* nqw    = (const float*)d_in[7];
  const float* nkw    = (const float*)d_in[8];
  const float* naqw   = (const float*)d_in[9];
  const float* nakw   = (const float*)d_in[10];
  const float* Wout   = (const float*)d_in[11];
  const float* bout   = (const float*)d_in[12];
  const float* Wadd   = (const float*)d_in[13];
  const float* badd   = (const float*)d_in[14];
  float* out_img = (float*)d_out;
  float* out_enc = (float*)d_out + (size_t)S_IMG * DMODEL;

  char* ws = (char*)d_ws;
  size_t off = 0;
  auto alloc = [&](size_t bytes) {
    char* p = ws + off;
    off += (bytes + 255) & ~(size_t)255;
    return p;
  };
  uint16_t* hs_bf   = (uint16_t*)alloc((size_t)S_IMG * DMODEL * 2);
  uint16_t* enc_bf  = (uint16_t*)alloc((size_t)S_TXT * DMODEL * 2);
  char*     wqkv_base = alloc((size_t)N_QKV * DMODEL * 2 * 2);  // WqkvT + WqkvaT (reused later)
  uint16_t* WqkvT   = (uint16_t*)wqkv_base;
  uint16_t* WqkvaT  = (uint16_t*)(wqkv_base + (size_t)N_QKV * DMODEL * 2);
  uint16_t* WoutT   = (uint16_t*)alloc((size_t)DMODEL * INNER * 2);
  uint16_t* WaddT   = (uint16_t*)alloc((size_t)DMODEL * INNER * 2);
  uint16_t* qkv_img = (uint16_t*)alloc((size_t)S_IMG * N_QKV * 2);
  uint16_t* qkv_txt = (uint16_t*)alloc((size_t)S_TXT * N_QKV * 2);
  // overlay Q/K/VT/attn on the Wqkv(T) region (dead after qkv GEMM): 37.8MB < 50.3MB
  uint16_t* Qb   = (uint16_t*)wqkv_base;
  uint16_t* Kb   = Qb + (size_t)HEADS * S_ALL * HD;
  uint16_t* VTb  = Kb + (size_t)HEADS * S_ALL * HD;
  uint16_t* attn = VTb + (size_t)HEADS * S_ALL * HD;

  k_cvt<<<1024, 256, 0, stream>>>(hidden, hs_bf, S_IMG * DMODEL / 4);
  k_cvt<<<256, 256, 0, stream>>>(enc, enc_bf, S_TXT * DMODEL / 4);
  k_cvt_t<<<(DMODEL / 64) * (N_QKV / 64), 256, 0, stream>>>(Wqkv, WqkvT, DMODEL, N_QKV);
  k_cvt_t<<<(DMODEL / 64) * (N_QKV / 64), 256, 0, stream>>>(Wqkva, WqkvaT, DMODEL, N_QKV);
  k_cvt_t<<<(INNER / 64) * (DMODEL / 64), 256, 0, stream>>>(Wout, WoutT, INNER, DMODEL);
  k_cvt_t<<<(INNER / 64) * (DMODEL / 64), 256, 0, stream>>>(Wadd, WaddT, INNER, DMODEL);

  dim3 gq(N_QKV / 128, (S_TXT + S_IMG) / 256);
  k_gemm2<true><<<gq, 512, 0, stream>>>(enc_bf, WqkvaT, bqkva, qkv_txt,
                                        hs_bf, WqkvT, nullptr, qkv_img,
                                        1, N_QKV, DMODEL);

  k_post<<<S_ALL, 256, 0, stream>>>(qkv_img, qkv_txt, fcos, fsin,
                                    nqw, nkw, naqw, nakw, Qb, Kb, VTb);

  k_attn<<<HEADS * (S_ALL / 64), 256, 0, stream>>>(Qb, Kb, VTb, attn);

  dim3 go(DMODEL / 128, S_ALL / 256);
  k_gemm2<false><<<go, 512, 0, stream>>>(attn, WaddT, badd, out_enc,
                                         attn + (size_t)S_TXT * INNER, WoutT, bout, out_img,
                                         1, DMODEL, DMODEL);
}

// Round 5
// 252.113 us; speedup vs baseline: 1.4753x; 1.0388x over previous
//
#include <hip/hip_runtime.h>
#include <stdint.h>

#define HEADS 16
#define HD 128
#define S_TXT 256
#define S_IMG 2048
#define S_ALL 2304
#define DMODEL 2048
#define N_QKV 6144
#define INNER 2048
#define ATT_EPS 1e-5f
#define ATT_SCALE 0.08838834764831845f
#define LOG2E 1.4426950408889634f
#define MBOUND 16.5f
#define QT_N 18      // 2304 / 128
#define TPS 36       // KV tiles (of 32) per split

typedef __attribute__((ext_vector_type(8))) __bf16 bf16x8;
typedef __attribute__((ext_vector_type(4))) float f32x4;
typedef __attribute__((ext_vector_type(4))) uint32_t u32x4;

__device__ __forceinline__ uint16_t f2bf(float f) {
  union { float f; uint32_t u; } v; v.f = f;
  uint32_t r = (v.u + 0x7FFF + ((v.u >> 16) & 1)) >> 16;
  return (uint16_t)r;
}
__device__ __forceinline__ float bf2f(uint16_t h) {
  union { float f; uint32_t u; } v; v.u = ((uint32_t)h) << 16;
  return v.f;
}
__device__ __forceinline__ float fexp2(float x) {
#if __has_builtin(__builtin_amdgcn_exp2f)
  return __builtin_amdgcn_exp2f(x);
#else
  return __expf(x * 0.69314718055994531f);
#endif
}

// async global->LDS, 16B per lane; lds ptr is wave-uniform base (HW adds lane*16)
__device__ __forceinline__ void async_cp16(const void* g, void* l) {
  __builtin_amdgcn_global_load_lds(
      (const __attribute__((address_space(1))) void*)g,
      (__attribute__((address_space(3))) void*)l, 16, 0, 0);
}

// ---------------- converts ----------------
__global__ __launch_bounds__(256) void k_cvt(const float* __restrict__ src,
                                             uint16_t* __restrict__ dst, int n4) {
  int i = blockIdx.x * 256 + threadIdx.x;
  int stride = gridDim.x * 256;
  for (; i < n4; i += stride) {
    float4 v = ((const float4*)src)[i];
    uint16_t o[4];
    o[0] = f2bf(v.x); o[1] = f2bf(v.y); o[2] = f2bf(v.z); o[3] = f2bf(v.w);
    ((uint2*)dst)[i] = *(const uint2*)o;
  }
}

// four transposing converts merged into one launch.  dst[C][R] = bf16(src[R][C])
__global__ __launch_bounds__(256) void k_cvt_t4(
    const float* __restrict__ s0, uint16_t* __restrict__ d0,
    const float* __restrict__ s1, uint16_t* __restrict__ d1,
    const float* __restrict__ s2, uint16_t* __restrict__ d2,
    const float* __restrict__ s3, uint16_t* __restrict__ d3) {
  __shared__ float t[64][68];
  int b = blockIdx.x;
  const float* src; uint16_t* dst; int R, C, tb;
  if (b < 3072)      { src = s0; dst = d0; R = DMODEL; C = N_QKV;  tb = b; }
  else if (b < 6144) { src = s1; dst = d1; R = DMODEL; C = N_QKV;  tb = b - 3072; }
  else if (b < 7168) { src = s2; dst = d2; R = INNER;  C = DMODEL; tb = b - 6144; }
  else               { src = s3; dst = d3; R = INNER;  C = DMODEL; tb = b - 7168; }
  int ntr = R >> 6;
  int tr = tb % ntr, tc = tb / ntr;
  int tid = threadIdx.x;
  int rr = tid >> 4, c4 = (tid & 15) * 4;
#pragma unroll
  for (int j = 0; j < 4; ++j) {
    int r = rr + j * 16;
    float4 v = *(const float4*)&src[(size_t)(tr * 64 + r) * C + tc * 64 + c4];
    *(float4*)&t[r][c4] = v;
  }
  __syncthreads();
  int cc = tid >> 4, r4 = (tid & 15) * 4;
#pragma unroll
  for (int j = 0; j < 4; ++j) {
    int c = cc + j * 16;
    uint16_t ov[4];
    ov[0] = f2bf(t[r4 + 0][c]); ov[1] = f2bf(t[r4 + 1][c]);
    ov[2] = f2bf(t[r4 + 2][c]); ov[3] = f2bf(t[r4 + 3][c]);
    *(uint2*)&dst[(size_t)(tc * 64 + c) * R + tr * 64 + r4] = *(const uint2*)ov;
  }
}

// ---------------- deep-pipelined GEMM ----------------
// C[M][N] = A[M][K](bf16) * BT[N][K](bf16) + bias.  BM=256, BN=128, BK=64.
// 8 waves (4M x 2N). Triple-buffered LDS, counted vmcnt(6), XOR swizzle, setprio.
template <bool OUT_BF16>
__global__ __launch_bounds__(512, 1) void k_gemm2(
    const uint16_t* __restrict__ A0, const uint16_t* __restrict__ B0,
    const float* __restrict__ bias0, void* __restrict__ C0,
    const uint16_t* __restrict__ A1, const uint16_t* __restrict__ B1,
    const float* __restrict__ bias1, void* __restrict__ C1,
    int seg0_tiles, int N, int K) {
  __shared__ __align__(16) char lds[3 * 49152];  // per buf: A 32KB + B 16KB
  int bn = blockIdx.x, bm = blockIdx.y;
  const uint16_t* A; const uint16_t* B; const float* bias; void* C; int mrow;
  if (bm < seg0_tiles) { A = A0; B = B0; bias = bias0; C = C0; mrow = bm * 256; }
  else { A = A1; B = B1; bias = bias1; C = C1; mrow = (bm - seg0_tiles) * 256; }
  int tid = threadIdx.x, lane = tid & 63, w = tid >> 6;
  int g = lane >> 4, li = lane & 15;
  int wm = w >> 1, wn = w & 1;
  const int NKI = K / 64;

  int rowin = lane >> 3;
  int csrc = (lane & 7) ^ rowin;

  auto stage = [&](int t, char* buf) {
    int kt = t * 64;
#pragma unroll
    for (int j = 0; j < 4; ++j) {
      int r = w * 4 + j;
      int tr = r * 8 + rowin;
      async_cp16(A + (size_t)(mrow + tr) * K + kt + 8 * csrc, buf + r * 1024);
    }
#pragma unroll
    for (int j = 0; j < 2; ++j) {
      int r = w * 2 + j;
      int tr = r * 8 + rowin;
      async_cp16(B + (size_t)(bn * 128 + tr) * K + kt + 8 * csrc, buf + 32768 + r * 1024);
    }
  };

  f32x4 acc[4][4] = {};

  stage(0, lds);
  stage(1, lds + 49152);
  asm volatile("s_waitcnt vmcnt(6)" ::: "memory");
  __builtin_amdgcn_s_barrier();
  asm volatile("" ::: "memory");

  int cbuf = 0, sbuf = 2;
  for (int t = 0; t < NKI; ++t) {
    const char* cur = lds + cbuf * 49152;
    if (t + 2 < NKI) stage(t + 2, lds + sbuf * 49152);

    bf16x8 af[2][4], bfv[2][4];
#pragma unroll
    for (int kk = 0; kk < 2; ++kk) {
#pragma unroll
      for (int mi = 0; mi < 4; ++mi) {
        int row = wm * 64 + mi * 16 + li;
        int ch = (kk * 4 + g) ^ (row & 7);
        af[kk][mi] = __builtin_bit_cast(bf16x8, *(const u32x4*)(cur + row * 128 + ch * 16));
      }
#pragma unroll
      for (int ni = 0; ni < 4; ++ni) {
        int row = wn * 64 + ni * 16 + li;
        int ch = (kk * 4 + g) ^ (row & 7);
        bfv[kk][ni] = __builtin_bit_cast(bf16x8, *(const u32x4*)(cur + 32768 + row * 128 + ch * 16));
      }
    }
    __builtin_amdgcn_s_setprio(1);
#pragma unroll
    for (int kk = 0; kk < 2; ++kk)
#pragma unroll
      for (int mi = 0; mi < 4; ++mi)
#pragma unroll
        for (int ni = 0; ni < 4; ++ni)
          acc[mi][ni] = __builtin_amdgcn_mfma_f32_16x16x32_bf16(af[kk][mi], bfv[kk][ni], acc[mi][ni], 0, 0, 0);
    __builtin_amdgcn_s_setprio(0);

    if (t + 1 < NKI) {
      if (t + 2 < NKI) asm volatile("s_waitcnt vmcnt(6)" ::: "memory");
      else             asm volatile("s_waitcnt vmcnt(0)" ::: "memory");
      __builtin_amdgcn_s_barrier();
      asm volatile("" ::: "memory");
    }
    cbuf = (cbuf + 1 == 3) ? 0 : cbuf + 1;
    sbuf = (sbuf + 1 == 3) ? 0 : sbuf + 1;
  }

#pragma unroll
  for (int mi = 0; mi < 4; ++mi) {
#pragma unroll
    for (int ni = 0; ni < 4; ++ni) {
      int col = bn * 128 + wn * 64 + ni * 16 + li;
      float bv = bias ? bias[col] : 0.0f;
#pragma unroll
      for (int i = 0; i < 4; ++i) {
        int r = mrow + wm * 64 + mi * 16 + 4 * g + i;
        float v = acc[mi][ni][i] + bv;
        if (OUT_BF16) ((uint16_t*)C)[(size_t)r * N + col] = f2bf(v);
        else          ((float*)C)[(size_t)r * N + col] = v;
      }
    }
  }
}

// ---------------- postprocess: rmsnorm + rope + scale*log2e; Q,K [H][S][D], V^T [H][D][S] ----------------
__global__ __launch_bounds__(256) void k_post(
    const uint16_t* __restrict__ qkv_img, const uint16_t* __restrict__ qkv_txt,
    const float* __restrict__ fcos, const float* __restrict__ fsin,
    const float* __restrict__ wq, const float* __restrict__ wk,
    const float* __restrict__ waq, const float* __restrict__ wak,
    uint16_t* __restrict__ Qo, uint16_t* __restrict__ Ko, uint16_t* __restrict__ VTo) {
  int s = blockIdx.x;
  const uint16_t* row = (s < S_TXT) ? qkv_txt + (size_t)s * N_QKV
                                    : qkv_img + (size_t)(s - S_TXT) * N_QKV;
  const float* wqp = (s < S_TXT) ? waq : wq;
  const float* wkp = (s < S_TXT) ? wak : wk;
  int tid = threadIdx.x, lane = tid & 63, w = tid >> 6;
  int h = w * 4 + (lane >> 4);
  int d0 = (lane & 15) * 8;
  float cs[8], sn[8];
#pragma unroll
  for (int j = 0; j < 8; ++j) {
    cs[j] = fcos[s * HD + d0 + j];
    sn[j] = fsin[s * HD + d0 + j];
  }
#pragma unroll
  for (int part = 0; part < 2; ++part) {  // 0 = Q, 1 = K
    const uint16_t* src = row + part * INNER + h * HD + d0;
    u32x4 raw = *(const u32x4*)src;
    const uint16_t* rp = (const uint16_t*)&raw;
    float x[8], ss = 0.f;
#pragma unroll
    for (int j = 0; j < 8; ++j) { x[j] = bf2f(rp[j]); ss += x[j] * x[j]; }
    ss += __shfl_xor(ss, 1); ss += __shfl_xor(ss, 2);
    ss += __shfl_xor(ss, 4); ss += __shfl_xor(ss, 8);
    float rn = rsqrtf(ss * (1.0f / HD) + ATT_EPS);
    const float* wp = part ? wkp : wqp;
#pragma unroll
    for (int j = 0; j < 8; ++j) x[j] = x[j] * rn * wp[d0 + j];
    float y[8];
#pragma unroll
    for (int j = 0; j < 8; j += 2) {
      y[j]     = x[j] * cs[j] - x[j + 1] * sn[j];
      y[j + 1] = x[j + 1] * cs[j + 1] + x[j] * sn[j + 1];
    }
    float sc = part ? 1.0f : (ATT_SCALE * LOG2E);
    uint16_t ov[8];
#pragma unroll
    for (int j = 0; j < 8; ++j) ov[j] = f2bf(y[j] * sc);
    uint16_t* dst = (part ? Ko : Qo) + ((size_t)h * S_ALL + s) * HD + d0;
    *(u32x4*)dst = *(const u32x4*)ov;
  }
  {  // V -> V^T scatter
    u32x4 raw = *(const u32x4*)(row + 2 * INNER + h * HD + d0);
    const uint16_t* rp = (const uint16_t*)&raw;
#pragma unroll
    for (int j = 0; j < 8; ++j)
      VTo[((size_t)h * HD + d0 + j) * S_ALL + s] = rp[j];
  }
}

// ---------------- attention (split-KV, self-contained waves) ----------------
// QBLK=128 (4 waves x 32q), KVBLK=32, SPLIT=2 (1152 keys/block). Swapped QK^T
// (mfma(K,Q)) makes P lane-local per q-row -> pack to 4 ds_write_b64; PV reads
// P back as A-frags (2 b128). Fixed-max softmax -> partials additive; fp32
// partial O + lsum to global; tiny combine kernel. One barrier per tile.
__global__ __launch_bounds__(256, 3) void k_attn(
    const uint16_t* __restrict__ Qg, const uint16_t* __restrict__ Kg,
    const uint16_t* __restrict__ VTg,
    float* __restrict__ part0, float* __restrict__ part1,
    float* __restrict__ lsumP) {
  __shared__ __align__(16) char Kt[2][8192];       // [32 key][128 d], chunk^=(row&15)
  __shared__ __align__(16) char Vt[2][8192];       // [128 d][32 s], chunk^=((row>>1)&3)
  __shared__ __align__(16) uint16_t Pl[4][32 * 40];  // per wave: [32 q][32 key + pad]

  int b0 = blockIdx.x;
  int bid = (b0 & 7) * 72 + (b0 >> 3);  // XCD-chunked: 4 (h,sp) groups per XCD
  int h = bid / 36, r6 = bid % 36, sp = r6 / 18, qt = r6 % 18;
  int tid = threadIdx.x, lane = tid & 63, w = tid >> 6;
  int g = lane >> 4, li = lane & 15;

  const uint16_t* Kh = Kg + (size_t)h * S_ALL * HD;
  const uint16_t* Vh = VTg + (size_t)h * HD * S_ALL;
  float* po = (sp ? part1 : part0) + ((size_t)(h * QT_N + qt) * 128 + w * 32) * 128;

  int qbase = qt * 128 + w * 32;
  bf16x8 qf[2][4];
#pragma unroll
  for (int q2 = 0; q2 < 2; ++q2) {
    const uint16_t* qp = Qg + ((size_t)h * S_ALL + qbase + q2 * 16 + li) * HD;
#pragma unroll
    for (int kc = 0; kc < 4; ++kc)
      qf[q2][kc] = __builtin_bit_cast(bf16x8, *(const u32x4*)(qp + kc * 32 + g * 8));
  }
  f32x4 o[2][8] = {};
  float lsum[2] = {0.f, 0.f};

  auto stage = [&](int tk, int buf) {
#pragma unroll
    for (int j = 0; j < 2; ++j) {  // K: 512 chunks, this wave: w*128+j*64+lane
      int cj = w * 128 + j * 64 + lane;
      int row = cj >> 4, c = (cj & 15) ^ (row & 15);
      async_cp16(Kh + (size_t)(tk * 32 + row) * HD + 8 * c, Kt[buf] + (w * 128 + j * 64) * 16);
    }
#pragma unroll
    for (int j = 0; j < 2; ++j) {  // V^T: 128 rows x 4 chunks
      int cj = w * 128 + j * 64 + lane;
      int row = cj >> 2, c = (cj & 3) ^ ((row >> 1) & 3);
      async_cp16(Vh + (size_t)row * S_ALL + tk * 32 + 8 * c, Vt[buf] + (w * 128 + j * 64) * 16);
    }
  };

  int t0 = sp * TPS;
  stage(t0, 0);
  asm volatile("s_waitcnt vmcnt(0)" ::: "memory");
  __builtin_amdgcn_s_barrier();
  asm volatile("" ::: "memory");

  for (int t = 0; t < TPS; ++t) {
    int cur = t & 1;
    if (t + 1 < TPS) stage(t0 + t + 1, cur ^ 1);
    const char* KtC = Kt[cur];
    const char* VtC = Vt[cur];

    // swapped QK^T: sc[q2][kb] = K[kb-half] . Q[q2-half]; C[row=key_local][col=q]
    f32x4 sc[2][2];
#pragma unroll
    for (int q2 = 0; q2 < 2; ++q2)
#pragma unroll
      for (int kb = 0; kb < 2; ++kb)
        sc[q2][kb] = (f32x4){-MBOUND, -MBOUND, -MBOUND, -MBOUND};
    __builtin_amdgcn_s_setprio(1);
#pragma unroll
    for (int kb = 0; kb < 2; ++kb)
#pragma unroll
      for (int kc = 0; kc < 4; ++kc) {
        int ch = (kc * 4 + g) ^ li;  // key&15 == li
        bf16x8 kf = __builtin_bit_cast(bf16x8,
            *(const u32x4*)(KtC + (kb * 16 + li) * 256 + ch * 16));
        sc[0][kb] = __builtin_amdgcn_mfma_f32_16x16x32_bf16(kf, qf[0][kc], sc[0][kb], 0, 0, 0);
        sc[1][kb] = __builtin_amdgcn_mfma_f32_16x16x32_bf16(kf, qf[1][kc], sc[1][kb], 0, 0, 0);
      }
    __builtin_amdgcn_s_setprio(0);

    // fixed-max softmax; lane holds q=q2*16+li, keys kb*16+4g+i -> pack pairs, b64 writes
    uint16_t* Pw = &Pl[w][0];
#pragma unroll
    for (int q2 = 0; q2 < 2; ++q2)
#pragma unroll
      for (int kb = 0; kb < 2; ++kb) {
        float p0 = fexp2(sc[q2][kb][0]);
        float p1 = fexp2(sc[q2][kb][1]);
        float p2 = fexp2(sc[q2][kb][2]);
        float p3 = fexp2(sc[q2][kb][3]);
        lsum[q2] += (p0 + p1) + (p2 + p3);
        uint2 pk;
        pk.x = (uint32_t)f2bf(p0) | ((uint32_t)f2bf(p1) << 16);
        pk.y = (uint32_t)f2bf(p2) | ((uint32_t)f2bf(p3) << 16);
        *(uint2*)((char*)Pw + (q2 * 16 + li) * 80 + kb * 32 + g * 8) = pk;
      }

    // PV: A = P rows (q), B = V^T
    bf16x8 pf[2];
#pragma unroll
    for (int q2 = 0; q2 < 2; ++q2)
      pf[q2] = __builtin_bit_cast(bf16x8,
          *(const u32x4*)((const char*)Pw + (q2 * 16 + li) * 80 + g * 16));
    __builtin_amdgcn_s_setprio(1);
#pragma unroll
    for (int db = 0; db < 8; ++db) {
      int vrow = db * 16 + li;
      int ch = g ^ ((vrow >> 1) & 3);
      bf16x8 vf = __builtin_bit_cast(bf16x8, *(const u32x4*)(VtC + vrow * 64 + ch * 16));
      o[0][db] = __builtin_amdgcn_mfma_f32_16x16x32_bf16(pf[0], vf, o[0][db], 0, 0, 0);
      o[1][db] = __builtin_amdgcn_mfma_f32_16x16x32_bf16(pf[1], vf, o[1][db], 0, 0, 0);
    }
    __builtin_amdgcn_s_setprio(0);

    asm volatile("s_waitcnt vmcnt(0)" ::: "memory");  // next tile staged (hidden under compute)
    __builtin_amdgcn_s_barrier();
    asm volatile("" ::: "memory");
  }

  // lsum: reduce across g-groups (lanes li, li+16, li+32, li+48)
#pragma unroll
  for (int q2 = 0; q2 < 2; ++q2) {
    float v = lsum[q2];
    v += __shfl_xor(v, 16);
    v += __shfl_xor(v, 32);
    lsum[q2] = v;
  }
  if (lane < 16) {
#pragma unroll
    for (int q2 = 0; q2 < 2; ++q2)
      lsumP[((size_t)sp * HEADS + h) * S_ALL + qbase + q2 * 16 + lane] = lsum[q2];
  }
  // partial O (fp32): row = q2*16+4g+i, col = db*16+li
#pragma unroll
  for (int q2 = 0; q2 < 2; ++q2)
#pragma unroll
    for (int db = 0; db < 8; ++db)
#pragma unroll
      for (int i = 0; i < 4; ++i)
        po[(q2 * 16 + 4 * g + i) * 128 + db * 16 + li] = o[q2][db][i];
}

// combine: attn[q][h*128+d] = bf16((p0+p1) / (l0+l1))
__global__ __launch_bounds__(256) void k_comb(
    const float* __restrict__ p0, const float* __restrict__ p1,
    const float* __restrict__ lsumP, uint16_t* __restrict__ attn) {
  int q = blockIdx.x, qt = q >> 7, ql = q & 127;
#pragma unroll
  for (int rep = 0; rep < 2; ++rep) {
    int d4 = threadIdx.x + rep * 256;   // 0..511 float4s
    int d = d4 * 4, h = d >> 7, dl = d & 127;
    size_t off = (((size_t)h * QT_N + qt) * 128 + ql) * 128 + dl;
    float4 a = *(const float4*)&p0[off];
    float4 b = *(const float4*)&p1[off];
    float l0 = lsumP[(size_t)h * S_ALL + q];
    float l1 = lsumP[((size_t)HEADS + h) * S_ALL + q];
    float inv = 1.0f / (l0 + l1);
    uint16_t ov[4];
    ov[0] = f2bf((a.x + b.x) * inv); ov[1] = f2bf((a.y + b.y) * inv);
    ov[2] = f2bf((a.z + b.z) * inv); ov[3] = f2bf((a.w + b.w) * inv);
    *(uint2*)&attn[(size_t)q * INNER + d] = *(const uint2*)ov;
  }
}

// ---------------- launch ----------------
extern "C" void kernel_launch(void* const* d_in, const int* in_sizes, int n_in,
                              void* d_out, int out_size, void* d_ws, size_t ws_size,
                              hipStream_t stream) {
  const float* hidden = (const float*)d_in[0];
  const float* enc    = (const float*)d_in[1];
  const float* fcos   = (const float*)d_in[2];
  const float* fsin   = (const float*)d_in[3];
  const float* Wqkv   = (const float*)d_in[4];
  const float* Wqkva  = (const float*)d_in[5];
  const float* bqkva  = (const float*)d_in[6];
  const float* nqw    = (const float*)d_in[7];
  const float* nkw    = (const float*)d_in[8];
  const float* naqw   = (const float*)d_in[9];
  const float* nakw   = (const float*)d_in[10];
  const float* Wout   = (const float*)d_in[11];
  const float* bout   = (const float*)d_in[12];
  const float* Wadd   = (const float*)d_in[13];
  const float* badd   = (const float*)d_in[14];
  float* out_img = (float*)d_out;
  float* out_enc = (float*)d_out + (size_t)S_IMG * DMODEL;

  char* ws = (char*)d_ws;
  size_t off = 0;
  auto alloc = [&](size_t bytes) {
    char* p = ws + off;
    off += (bytes + 255) & ~(size_t)255;
    return p;
  };
  uint16_t* hs_bf   = (uint16_t*)alloc((size_t)S_IMG * DMODEL * 2);
  uint16_t* enc_bf  = (uint16_t*)alloc((size_t)S_TXT * DMODEL * 2);
  char*     wqkv_base = alloc((size_t)N_QKV * DMODEL * 2 * 2);  // WqkvT + WqkvaT (reused later)
  uint16_t* WqkvT   = (uint16_t*)wqkv_base;
  uint16_t* WqkvaT  = (uint16_t*)(wqkv_base + (size_t)N_QKV * DMODEL * 2);
  uint16_t* WoutT   = (uint16_t*)alloc((size_t)DMODEL * INNER * 2);
  uint16_t* WaddT   = (uint16_t*)alloc((size_t)DMODEL * INNER * 2);
  uint16_t* qkv_img = (uint16_t*)alloc((size_t)S_IMG * N_QKV * 2);
  uint16_t* qkv_txt = (uint16_t*)alloc((size_t)S_TXT * N_QKV * 2);
  // overlay Q/K/VT/attn on the Wqkv(T) region (dead after qkv GEMM)
  uint16_t* Qb   = (uint16_t*)wqkv_base;
  uint16_t* Kb   = Qb + (size_t)HEADS * S_ALL * HD;
  uint16_t* VTb  = Kb + (size_t)HEADS * S_ALL * HD;
  uint16_t* attn = VTb + (size_t)HEADS * S_ALL * HD;
  // attention partials: split0 -> d_out (free until final GEMM), split1 -> dead qkv_img,
  // lsum partials -> dead enc_bf region
  float* part0 = (float*)d_out;       // 2304*2048*4 = 18.87MB = out_size exactly
  float* part1 = (float*)qkv_img;     // 25.2MB region, need 18.87MB
  float* lsumP = (float*)enc_bf;      // 1.05MB region, need 295KB

  k_cvt<<<1024, 256, 0, stream>>>(hidden, hs_bf, S_IMG * DMODEL / 4);
  k_cvt<<<256, 256, 0, stream>>>(enc, enc_bf, S_TXT * DMODEL / 4);
  k_cvt_t4<<<8192, 256, 0, stream>>>(Wqkv, WqkvT, Wqkva, WqkvaT, Wout, WoutT, Wadd, WaddT);

  dim3 gq(N_QKV / 128, (S_TXT + S_IMG) / 256);
  k_gemm2<true><<<gq, 512, 0, stream>>>(enc_bf, WqkvaT, bqkva, qkv_txt,
                                        hs_bf, WqkvT, nullptr, qkv_img,
                                        1, N_QKV, DMODEL);

  k_post<<<S_ALL, 256, 0, stream>>>(qkv_img, qkv_txt, fcos, fsin,
                                    nqw, nkw, naqw, nakw, Qb, Kb, VTb);

  k_attn<<<HEADS * QT_N * 2, 256, 0, stream>>>(Qb, Kb, VTb, part0, part1, lsumP);
  k_comb<<<S_ALL, 256, 0, stream>>>(part0, part1, lsumP, attn);

  dim3 go(DMODEL / 128, S_ALL / 256);
  k_gemm2<false><<<go, 512, 0, stream>>>(attn, WaddT, badd, out_enc,
                                         attn + (size_t)S_TXT * INNER, WoutT, bout, out_img,
                                         1, DMODEL, DMODEL);
}